// Round 6
// baseline (317.556 us; speedup 1.0000x reference)
//
#include <hip/hip_runtime.h>
#include <hip/hip_bf16.h>

typedef unsigned short u16;
typedef unsigned int   u32;
typedef __attribute__((ext_vector_type(8))) short bf16x8;
typedef __attribute__((ext_vector_type(4))) short bf16x4;
typedef __attribute__((ext_vector_type(4))) float f32x4;
typedef __attribute__((ext_vector_type(4))) unsigned short u16x4;

__device__ __forceinline__ u16 f32_to_bf16bits(float f) {
    u32 x = __float_as_uint(f);
    u32 r = (x + 0x7fffu + ((x >> 16) & 1u)) >> 16;   // RNE
    return (u16)r;
}
__device__ __forceinline__ float bf16bits_to_f32(u16 u) {
    return __uint_as_float(((u32)u) << 16);
}
__device__ __forceinline__ u32 cvt_pk_bf16(float lo, float hi) {
    u32 r;
    asm("v_cvt_pk_bf16_f32 %0, %1, %2" : "=v"(r) : "v"(lo), "v"(hi));
    return r;
}

// async global->LDS, 16B per lane. LDS dest is wave-uniform base + lane*16.
__device__ __forceinline__ void async_copy16(void* lds, const void* g) {
    __builtin_amdgcn_global_load_lds(
        (__attribute__((address_space(1))) void*)(g),
        (__attribute__((address_space(3))) void*)(lds), 16, 0, 0);
}

#define VMC6() asm volatile("s_waitcnt vmcnt(6)" ::: "memory")
#define VMC0() asm volatile("s_waitcnt vmcnt(0)" ::: "memory")
#define ENDBAR() __builtin_amdgcn_s_barrier()

// ---------------------------------------------------------------- convert x
__global__ void convert_f32_bf16(const float* __restrict__ src, u16* __restrict__ dst, int n4) {
    const int i = blockIdx.x * 256 + threadIdx.x;
    if (i >= n4) return;
    const float4 v = ((const float4*)src)[i];
    u16x4 o = { f32_to_bf16bits(v.x), f32_to_bf16bits(v.y),
                f32_to_bf16bits(v.z), f32_to_bf16bits(v.w) };
    ((u16x4*)dst)[i] = o;
}

// ------------------------------------------- weight transpose fp32(K,N)->bf16(N,K)
__global__ void transpose_wT(const float* __restrict__ src, u16* __restrict__ dst,
                             int N, int dstStride) {
    __shared__ float tile[32][129];
    const int n0 = blockIdx.x * 128, k0 = blockIdx.y * 32;
    const int tx = threadIdx.x, ty = threadIdx.y;      // (32, 8)
#pragma unroll
    for (int j = 0; j < 4; ++j)
#pragma unroll
        for (int i = 0; i < 4; ++i)
            tile[ty + 8*j][tx + 32*i] = src[(size_t)(k0 + ty + 8*j) * N + n0 + tx + 32*i];
    __syncthreads();
    const int tid = ty * 32 + tx;
    const int c = tid & 15, nl0 = tid >> 4;
#pragma unroll
    for (int s = 0; s < 8; ++s) {
        const int nl = nl0 + s * 16;
        const u32 pk = (u32)f32_to_bf16bits(tile[2*c][nl])
                     | ((u32)f32_to_bf16bits(tile[2*c + 1][nl]) << 16);
        *(u32*)&dst[(size_t)(n0 + nl) * dstStride + k0 + 2*c] = pk;
    }
}

// ------------------------------------------- V transpose bf16 (s,dcol)->(dcol,s)
__global__ void transpose_v(const u16* __restrict__ qkv, u16* __restrict__ vT) {
    __shared__ u16 tile[32][34];
    const int s0 = blockIdx.x * 32, n0 = blockIdx.y * 32;
    const int tx = threadIdx.x, ty = threadIdx.y;
#pragma unroll
    for (int i = 0; i < 4; ++i)
        tile[ty + i*8][tx] = qkv[(size_t)(s0 + ty + i*8) * 6144 + 5120 + n0 + tx];
    __syncthreads();
#pragma unroll
    for (int i = 0; i < 4; ++i)
        vT[(size_t)(n0 + ty + i*8) * 2048 + s0 + tx] = tile[tx][ty + i*8];
}

// ---------------------------------------------------------------- RoPE in place
__global__ void rope_kernel(u32* __restrict__ qkv, const float* __restrict__ cosp,
                            const float* __restrict__ sinp) {
    const int s = blockIdx.x;
    const int h = blockIdx.y * 4 + (threadIdx.x >> 6);
    const int p = threadIdx.x & 63;
    const size_t off = ((size_t)s * 6144 + h * 128) >> 1;
    const u32 packed = qkv[off + p];
    const float c  = cosp[s*64 + p], sn = sinp[s*64 + p];
    const float t1 = bf16bits_to_f32((u16)(packed & 0xffffu));
    const float t2 = bf16bits_to_f32((u16)(packed >> 16));
    const float o1 = t1 * c - t2 * sn;
    const float o2 = t1 * sn + t2 * c;
    qkv[off + p] = (u32)f32_to_bf16bits(o1) | ((u32)f32_to_bf16bits(o2) << 16);
}

// ---------------------------------------------------------------- qkv GEMM
// C[2048,6144] = A[2048,4096] * B[6144,4096]^T.  BM=128, BN=384, BK=64.
// Grid 16x16 = 256 blocks (full chip).  8 waves (2m x 4n); wave = 64r x 96c.
// 8 phases / 2 ktiles; quadrant = 2m x 3n frags x 2dk = 12 MFMA/phase.
// LDS: A[2buf][2half][64][128B]=32KB at 0, B[2buf][2half][192][128B]=96KB at 32768.
// Counted vmcnt(6) at p3/p7 (tail: vmcnt(0) when guarded stages skipped).
#define Q_RD_A(d, mh) do { _Pragma("unroll")                                   \
    for (int mi = 0; mi < 2; ++mi) {                                           \
        const char* ab = sm + ((d)*2 + wm)*8192 + (((mh)*2+mi)*16 + c0)*128;   \
        af[mi][0] = *(const bf16x8*)(ab + ((g ^ (c0&7)) * 16));                \
        af[mi][1] = *(const bf16x8*)(ab + (((4+g) ^ (c0&7)) * 16));            \
    } } while (0)

#define Q_RD_B(d, nh) do { _Pragma("unroll")                                   \
    for (int ni = 0; ni < 3; ++ni) {                                           \
        const char* bb = sm + 32768 + ((d)*2 + bh)*24576                       \
                       + ((wn&1)*96 + ((nh)*3+ni)*16 + c0)*128;                \
        bf[(nh)*3+ni][0] = *(const bf16x8*)(bb + ((g ^ (c0&7)) * 16));         \
        bf[(nh)*3+ni][1] = *(const bf16x8*)(bb + (((4+g) ^ (c0&7)) * 16));     \
    } } while (0)

#define Q_MFMA(mh, nh) do {                                                    \
    __builtin_amdgcn_s_barrier();                                              \
    asm volatile("s_waitcnt lgkmcnt(0)" ::: "memory");                         \
    __builtin_amdgcn_sched_barrier(0);                                         \
    __builtin_amdgcn_s_setprio(1);                                             \
    _Pragma("unroll") for (int dk = 0; dk < 2; ++dk)                           \
    _Pragma("unroll") for (int mi = 0; mi < 2; ++mi)                           \
    _Pragma("unroll") for (int ni = 0; ni < 3; ++ni)                           \
        acc[(mh)*2+mi][(nh)*3+ni] = __builtin_amdgcn_mfma_f32_16x16x32_bf16(   \
            af[mi][dk], bf[(nh)*3+ni][dk], acc[(mh)*2+mi][(nh)*3+ni], 0,0,0);  \
    __builtin_amdgcn_s_setprio(0); } while (0)

__global__ __launch_bounds__(512, 2) void gemm_qkv(
    const u16* __restrict__ A, const u16* __restrict__ B, u16* __restrict__ C,
    const int N, const int K) {
    __shared__ __align__(16) char sm[131072];
    const int tid = threadIdx.x;
    const int w = tid >> 6, l = tid & 63;
    const int wm = w >> 2, wn = w & 3, bh = wn >> 1;
    const int g = l >> 4, c0 = l & 15;
    const int bm = blockIdx.x >> 4, bn = blockIdx.x & 15;

    const int srow   = w*8 + (l >> 3);
    const int schunk = (l & 7) ^ (l >> 3);
    const u16* Abase = A + (size_t)(bm*128 + srow) * K + schunk*8;
    const u16* Bbase = B + (size_t)(bn*384 + srow) * K + schunk*8;

    f32x4 acc[4][6] = {};
    bf16x8 af[2][2], bf[6][2];

    auto stageA = [&](int kt, int d, int h) {
        async_copy16(sm + (d*2 + h)*8192 + (w*8)*128,
                     Abase + (size_t)h*64*K + kt*64);
    };
    auto stageB = [&](int kt, int d, int h) {
        char* dst = sm + 32768 + (d*2 + h)*24576 + (w*8)*128;
        const u16* src = Bbase + (size_t)h*192*K + kt*64;
#pragma unroll
        for (int r = 0; r < 3; ++r)
            async_copy16(dst + r*8192, src + (size_t)r*64*K);
    };

    const int nkt = K >> 6;    // 64

    // prologue: ktile0 full + ktile1 B halves; retire ktile0, keep B1 in flight
    stageB(0, 0, 0); stageB(0, 0, 1);
    stageA(0, 0, 0); stageA(0, 0, 1);
    stageB(1, 1, 0); stageB(1, 1, 1);
    VMC6();
    __builtin_amdgcn_s_barrier();

    for (int t = 0; t < nkt; t += 2) {
        const int tb = t + 1, tc = t + 2, td = t + 3;
        // p0: ktile t (buf0) quad (m0, n0); stage A[1][0] <- t+1
        Q_RD_A(0, 0); Q_RD_B(0, 0); stageA(tb, 1, 0);
        Q_MFMA(0, 0); ENDBAR();
        // p1: (m0, n1); stage A[1][1]
        Q_RD_B(0, 1); stageA(tb, 1, 1);
        Q_MFMA(0, 1); ENDBAR();
        // p2: (m1, n0); stage B[0][0] <- t+2 (B[0] fully read by p1-end)
        Q_RD_A(0, 1); if (tc < nkt) stageB(tc, 0, 0);
        Q_MFMA(1, 0); ENDBAR();
        // p3: (m1, n1); stage B[0][1]; retire A(t+1)+older
        if (tc < nkt) { stageB(tc, 0, 1); Q_MFMA(1, 1); VMC6(); }
        else          { Q_MFMA(1, 1); VMC0(); }
        ENDBAR();
        // p4: ktile t+1 (buf1) (m0, n0); stage A[0][0] <- t+2
        Q_RD_A(1, 0); Q_RD_B(1, 0); if (tc < nkt) stageA(tc, 0, 0);
        Q_MFMA(0, 0); ENDBAR();
        // p5: (m0, n1); stage A[0][1]
        Q_RD_B(1, 1); if (tc < nkt) stageA(tc, 0, 1);
        Q_MFMA(0, 1); ENDBAR();
        // p6: (m1, n0); stage B[1][0] <- t+3
        Q_RD_A(1, 1); if (td < nkt) stageB(td, 1, 0);
        Q_MFMA(1, 0); ENDBAR();
        // p7: (m1, n1); stage B[1][1]; retire ktile t+2's stages
        if (td < nkt) { stageB(td, 1, 1); Q_MFMA(1, 1); VMC6(); }
        else          { Q_MFMA(1, 1); VMC0(); }
        ENDBAR();
    }
    VMC0();  // drain before LDS dealloc

#pragma unroll
    for (int m = 0; m < 4; ++m)
#pragma unroll
        for (int n = 0; n < 6; ++n) {
            const int row = bm*128 + wm*64 + m*16 + g*4;
            const int col = bn*384 + wn*96 + n*16 + c0;
#pragma unroll
            for (int r = 0; r < 4; ++r)
                C[(size_t)(row + r) * N + col] = f32_to_bf16bits(acc[m][n][r]);
        }
}
#undef Q_RD_A
#undef Q_RD_B
#undef Q_MFMA

// ---------------------------------------------------------------- out-proj GEMM
// C[2048,4096](f32) = A[2048,4096] * B[4096,4096]^T.  BM=128, BN=256, BK=64.
// Grid 16x16 = 256 blocks.  8 waves (2m x 4n); wave = 64r x 64c.
// TRIPLE-buffered LDS (3 x 48KB = 144KB); 2 phases/ktile, 16 MFMA/phase.
// During ktile t: stage ktile t+2 into buf (t+2)%3 (last read at t-1).
// vmcnt(6) once per ktile (allows t+2's 6 calls in flight; 4-5 phase lead).
#define O_RD_A(b, mh) do { _Pragma("unroll")                                   \
    for (int mi = 0; mi < 2; ++mi) {                                           \
        const char* ab = sm + (b)*49152 + (wm*64 + ((mh)*2+mi)*16 + c0)*128;   \
        af[mi][0] = *(const bf16x8*)(ab + ((g ^ (c0&7)) * 16));                \
        af[mi][1] = *(const bf16x8*)(ab + (((4+g) ^ (c0&7)) * 16));            \
    } } while (0)

#define O_RD_B(b) do { _Pragma("unroll")                                       \
    for (int nj = 0; nj < 4; ++nj) {                                           \
        const char* bb = sm + (b)*49152 + 16384 + (wn*64 + nj*16 + c0)*128;    \
        bf[nj][0] = *(const bf16x8*)(bb + ((g ^ (c0&7)) * 16));                \
        bf[nj][1] = *(const bf16x8*)(bb + (((4+g) ^ (c0&7)) * 16));            \
    } } while (0)

#define O_MFMA(mh) do {                                                        \
    __builtin_amdgcn_s_barrier();                                              \
    asm volatile("s_waitcnt lgkmcnt(0)" ::: "memory");                         \
    __builtin_amdgcn_sched_barrier(0);                                         \
    __builtin_amdgcn_s_setprio(1);                                             \
    _Pragma("unroll") for (int dk = 0; dk < 2; ++dk)                           \
    _Pragma("unroll") for (int mi = 0; mi < 2; ++mi)                           \
    _Pragma("unroll") for (int nj = 0; nj < 4; ++nj)                           \
        acc[(mh)*2+mi][nj] = __builtin_amdgcn_mfma_f32_16x16x32_bf16(          \
            af[mi][dk], bf[nj][dk], acc[(mh)*2+mi][nj], 0,0,0);                \
    __builtin_amdgcn_s_setprio(0); } while (0)

__global__ __launch_bounds__(512, 2) void gemm_out(
    const u16* __restrict__ A, const u16* __restrict__ B, float* __restrict__ C,
    const int N, const int K) {
    __shared__ __align__(16) char sm[147456];
    const int tid = threadIdx.x;
    const int w = tid >> 6, l = tid & 63;
    const int wm = w >> 2, wn = w & 3;
    const int g = l >> 4, c0 = l & 15;
    const int bm = blockIdx.x >> 4, bn = blockIdx.x & 15;

    const int srow   = w*8 + (l >> 3);
    const int schunk = (l & 7) ^ (l >> 3);
    const u16* Abase = A + (size_t)(bm*128 + srow) * K + schunk*8;
    const u16* Bbase = B + (size_t)(bn*256 + srow) * K + schunk*8;

    f32x4 acc[4][4] = {};
    bf16x8 af[2][2], bf[4][2];

    auto stage_p0 = [&](int kt, int b) {   // A rows 0-63, B rows 0-127
        char* base = sm + b*49152 + (w*8)*128;
        async_copy16(base,                 Abase + kt*64);
        async_copy16(base + 16384,         Bbase + kt*64);
        async_copy16(base + 16384 + 8192,  Bbase + (size_t)64*K + kt*64);
    };
    auto stage_p1 = [&](int kt, int b) {   // A rows 64-127, B rows 128-255
        char* base = sm + b*49152 + (w*8)*128;
        async_copy16(base + 8192,          Abase + (size_t)64*K  + kt*64);
        async_copy16(base + 16384 + 16384, Bbase + (size_t)128*K + kt*64);
        async_copy16(base + 16384 + 24576, Bbase + (size_t)192*K + kt*64);
    };

    const int nkt = K >> 6;    // 64

    // prologue: ktiles 0,1 into bufs 0,1; retire ktile0, keep ktile1 in flight
    stage_p0(0, 0); stage_p1(0, 0);
    stage_p0(1, 1); stage_p1(1, 1);
    VMC6();
    __builtin_amdgcn_s_barrier();

    int bc = 0;
    for (int t = 0; t < nkt; ++t) {
        const int b2 = (bc == 0) ? 2 : bc - 1;        // (bc+2)%3
        const bool st = (t + 2) < nkt;
        // phase 0: m-half 0, all n; stage half of ktile t+2
        O_RD_A(bc, 0); O_RD_B(bc);
        if (st) stage_p0(t + 2, b2);
        O_MFMA(0); ENDBAR();
        // phase 1: m-half 1; stage rest of ktile t+2; retire ktile t+1's stages
        O_RD_A(bc, 1);
        if (st) { stage_p1(t + 2, b2); O_MFMA(1); VMC6(); }
        else    { O_MFMA(1); VMC0(); }
        ENDBAR();
        bc = (bc == 2) ? 0 : bc + 1;
    }
    VMC0();  // drain before LDS dealloc

#pragma unroll
    for (int m = 0; m < 4; ++m)
#pragma unroll
        for (int n = 0; n < 4; ++n) {
            const int row = bm*128 + wm*64 + m*16 + g*4;
            const int col = bn*256 + wn*64 + n*16 + c0;
#pragma unroll
            for (int r = 0; r < 4; ++r)
                C[(size_t)(row + r) * N + col] = acc[m][n][r];
        }
}
#undef O_RD_A
#undef O_RD_B
#undef O_MFMA

// ---------------------------------------------------------------- flash attention
// (unchanged — validated rounds 2-4)
__global__ __launch_bounds__(256, 2) void attn_kernel(
    const u16* __restrict__ qkv, const u16* __restrict__ vT, u16* __restrict__ outp) {
    __shared__ __align__(16) char lds[65536];
    const int tid = threadIdx.x;
    const int w = tid >> 6, l = tid & 63;
    const int g = l >> 4, c0 = l & 15;
    const int qt = (blockIdx.y < 16) ? blockIdx.x : (15 - (int)blockIdx.x);
    const int h = blockIdx.y;
    const int kvh = h >> 2;
    const int q0g = qt * 128;
    const int qrow0 = q0g + w * 32;

    const int srK = w*4 + g,        scK = c0 ^ srK;
    const int srV = w*8 + (l >> 3), scV = (l & 7) ^ (l >> 3);

#pragma unroll
    for (int i = 0; i < 8; ++i)
        async_copy16(lds + (i*16 + w*4) * 256,
                     qkv + (size_t)(q0g + i*16 + srK) * 6144 + h*128 + scK*8);
    __syncthreads();

#pragma unroll
    for (int i = 0; i < 4; ++i)
        async_copy16(lds + 32768 + (i*16 + w*4) * 256,
                     qkv + (size_t)(i*16 + srK) * 6144 + 4096 + kvh*128 + scK*8);
#pragma unroll
    for (int i = 0; i < 4; ++i)
        async_copy16(lds + 49152 + (i*32 + w*8) * 128,
                     vT + (size_t)(kvh*128 + i*32 + srV) * 2048 + scV*8);

    bf16x8 qf[2][4];
#pragma unroll
    for (int i = 0; i < 2; ++i)
#pragma unroll
        for (int dks = 0; dks < 4; ++dks) {
            const int row = w*32 + i*16 + c0;
            qf[i][dks] = *(const bf16x8*)(lds + row*256 + (((dks*4 + g) ^ c0) * 16));
        }
    __syncthreads();

    f32x4 o[2][8] = {};
    float lsum[2] = {0.f, 0.f};
    const int ntiles = 2*qt + 2;
    const float SC2 = 0.08838834764831845f * 1.4426950408889634f;

    for (int kt = 0; kt < ntiles; ++kt) {
        const int cur = kt & 1;
        const char* kb = lds + (cur ? 0 : 32768);
        const char* vb = lds + (cur ? 16384 : 49152);
        if (kt + 1 < ntiles) {
            char* kbn = lds + ((cur ^ 1) ? 0 : 32768);
            char* vbn = lds + ((cur ^ 1) ? 16384 : 49152);
#pragma unroll
            for (int i = 0; i < 4; ++i)
                async_copy16(kbn + (i*16 + w*4) * 256,
                             qkv + (size_t)((kt+1)*64 + i*16 + srK) * 6144 + 4096 + kvh*128 + scK*8);
#pragma unroll
            for (int i = 0; i < 4; ++i)
                async_copy16(vbn + (i*32 + w*8) * 128,
                             vT + (size_t)(kvh*128 + i*32 + srV) * 2048 + (kt+1)*64 + scV*8);
        }

        if (kt*64 <= qrow0 + 31) {
            f32x4 st[2][4] = {};
            __builtin_amdgcn_s_setprio(1);
#pragma unroll
            for (int dks = 0; dks < 4; ++dks) {
                bf16x8 kf[4];
#pragma unroll
                for (int j = 0; j < 4; ++j) {
                    const int row = j*16 + c0;
                    kf[j] = *(const bf16x8*)(kb + row*256 + (((dks*4 + g) ^ c0) * 16));
                }
#pragma unroll
                for (int i = 0; i < 2; ++i)
#pragma unroll
                    for (int j = 0; j < 4; ++j)
                        st[i][j] = __builtin_amdgcn_mfma_f32_16x16x32_bf16(
                            kf[j], qf[i][dks], st[i][j], 0, 0, 0);
            }
            __builtin_amdgcn_s_setprio(0);

            const bool diag = (kt*64 + 63) > qrow0;
            u32 pk[2][4][2];
#pragma unroll
            for (int i = 0; i < 2; ++i) {
                float rowsum = 0.f;
#pragma unroll
                for (int j = 0; j < 4; ++j) {
#pragma unroll
                    for (int r = 0; r < 4; ++r) {
                        float p = exp2f(st[i][j][r] * SC2);
                        if (diag) {
                            const int kgl = kt*64 + j*16 + g*4 + r;
                            const int qgl = qrow0 + i*16 + c0;
                            if (kgl > qgl) p = 0.f;
                        }
                        st[i][j][r] = p;
                        rowsum += p;
                    }
                    pk[i][j][0] = cvt_pk_bf16(st[i][j][0], st[i][j][1]);
                    pk[i][j][1] = cvt_pk_bf16(st[i][j][2], st[i][j][3]);
                }
                rowsum += __shfl_xor(rowsum, 16);
                rowsum += __shfl_xor(rowsum, 32);
                lsum[i] += rowsum;
            }

#pragma unroll
            for (int dks = 0; dks < 2; ++dks) {
                bf16x8 pf[2];
#pragma unroll
                for (int i = 0; i < 2; ++i) {
                    union { u32 u[4]; bf16x8 v; } pu;
                    pu.u[0] = pk[i][2*dks][0];   pu.u[1] = pk[i][2*dks][1];
                    pu.u[2] = pk[i][2*dks+1][0]; pu.u[3] = pk[i][2*dks+1][1];
                    pf[i] = pu.v;
                }
                __builtin_amdgcn_s_setprio(1);
#pragma unroll
                for (int dj = 0; dj < 8; ++dj) {
                    const int row = dj*16 + c0;
                    const int cg0 = (4*dks + (g >> 1)) ^ (row & 7);
                    const int cg1 = (4*dks + (g >> 1) + 2) ^ (row & 7);
                    union { struct { bf16x4 lo, hi; } p; bf16x8 v; } vu;
                    vu.p.lo = *(const bf16x4*)(vb + row*128 + cg0*16 + 8*(g & 1));
                    vu.p.hi = *(const bf16x4*)(vb + row*128 + cg1*16 + 8*(g & 1));
#pragma unroll
                    for (int i = 0; i < 2; ++i)
                        o[i][dj] = __builtin_amdgcn_mfma_f32_16x16x32_bf16(
                            vu.v, pf[i], o[i][dj], 0, 0, 0);
                }
                __builtin_amdgcn_s_setprio(0);
            }
        }
        __syncthreads();
    }

#pragma unroll
    for (int i = 0; i < 2; ++i) {
        const float rcp = 1.0f / lsum[i];
        const int qg = qrow0 + i*16 + c0;
#pragma unroll
        for (int dj = 0; dj < 8; ++dj) {
            u16x4 ov = { f32_to_bf16bits(o[i][dj][0] * rcp),
                         f32_to_bf16bits(o[i][dj][1] * rcp),
                         f32_to_bf16bits(o[i][dj][2] * rcp),
                         f32_to_bf16bits(o[i][dj][3] * rcp) };
            *(u16x4*)(outp + (size_t)qg * 4096 + h*128 + dj*16 + g*4) = ov;
        }
    }
}

// ---------------------------------------------------------------- launcher
extern "C" void kernel_launch(void* const* d_in, const int* in_sizes, int n_in,
                              void* d_out, int out_size, void* d_ws, size_t ws_size,
                              hipStream_t stream) {
    const float* x    = (const float*)d_in[0];
    const float* wq   = (const float*)d_in[1];
    const float* wk   = (const float*)d_in[2];
    const float* wv   = (const float*)d_in[3];
    const float* wo   = (const float*)d_in[4];
    const float* cosp = (const float*)d_in[5];
    const float* sinp = (const float*)d_in[6];
    // d_in[7] = mask — causality applied analytically in attn_kernel.

    char* ws = (char*)d_ws;
    u16* xb    = (u16*)(ws);                       //  16.8 MB  x bf16 (2048x4096)
    u16* wqkvT = (u16*)(ws + 16777216);            //  50.3 MB  [wq|wk|wv]^T (6144x4096)
    u16* woT   = (u16*)(ws + 67108864);            //  33.6 MB  wo^T (4096x4096)
    u16* qkv   = (u16*)(ws + 100663296);           //  25.2 MB  qkv (2048x6144)
    u16* vTb   = (u16*)(ws + 125829120);           //   4.2 MB  v^T (1024x2048)
    u16* attn  = (u16*)(ws + 130023424);           //  16.8 MB  attn out (2048x4096)

    dim3 tb(32, 8);
    convert_f32_bf16<<<8192, 256, 0, stream>>>(x, xb, 2097152);
    transpose_wT<<<dim3(32, 128), tb, 0, stream>>>(wq, wqkvT, 4096, 4096);
    transpose_wT<<<dim3(8, 128),  tb, 0, stream>>>(wk, wqkvT + (size_t)4096*4096, 1024, 4096);
    transpose_wT<<<dim3(8, 128),  tb, 0, stream>>>(wv, wqkvT + (size_t)5120*4096, 1024, 4096);
    transpose_wT<<<dim3(32, 128), tb, 0, stream>>>(wo, woT, 4096, 4096);

    gemm_qkv<<<256, 512, 0, stream>>>(xb, wqkvT, qkv, 6144, 4096);
    rope_kernel<<<dim3(2048, 10), 256, 0, stream>>>((u32*)qkv, cosp, sinp);
    transpose_v<<<dim3(64, 32), tb, 0, stream>>>(qkv, vTb);
    attn_kernel<<<dim3(16, 32), 256, 0, stream>>>(qkv, vTb, attn);
    gemm_out<<<256, 512, 0, stream>>>(attn, woT, (float*)d_out, 4096, 4096);
}

// Round 7
// 315.082 us; speedup vs baseline: 1.0079x; 1.0079x over previous
//
#include <hip/hip_runtime.h>
#include <hip/hip_bf16.h>

typedef unsigned short u16;
typedef unsigned int   u32;
typedef __attribute__((ext_vector_type(8))) short bf16x8;
typedef __attribute__((ext_vector_type(4))) short bf16x4;
typedef __attribute__((ext_vector_type(4))) float f32x4;
typedef __attribute__((ext_vector_type(4))) unsigned short u16x4;

__device__ __forceinline__ u16 f32_to_bf16bits(float f) {
    u32 x = __float_as_uint(f);
    u32 r = (x + 0x7fffu + ((x >> 16) & 1u)) >> 16;   // RNE
    return (u16)r;
}
__device__ __forceinline__ float bf16bits_to_f32(u16 u) {
    return __uint_as_float(((u32)u) << 16);
}
__device__ __forceinline__ u32 cvt_pk_bf16(float lo, float hi) {
    u32 r;
    asm("v_cvt_pk_bf16_f32 %0, %1, %2" : "=v"(r) : "v"(lo), "v"(hi));
    return r;
}

// async global->LDS, 16B per lane. LDS dest is wave-uniform base + lane*16.
__device__ __forceinline__ void async_copy16(void* lds, const void* g) {
    __builtin_amdgcn_global_load_lds(
        (__attribute__((address_space(1))) void*)(g),
        (__attribute__((address_space(3))) void*)(lds), 16, 0, 0);
}

#define VMC6() asm volatile("s_waitcnt vmcnt(6)" ::: "memory")
#define VMC0() asm volatile("s_waitcnt vmcnt(0)" ::: "memory")
#define ENDBAR() __builtin_amdgcn_s_barrier()

// ---------------------------------------------------------------- convert x
__global__ void convert_f32_bf16(const float* __restrict__ src, u16* __restrict__ dst, int n4) {
    const int i = blockIdx.x * 256 + threadIdx.x;
    if (i >= n4) return;
    const float4 v = ((const float4*)src)[i];
    u16x4 o = { f32_to_bf16bits(v.x), f32_to_bf16bits(v.y),
                f32_to_bf16bits(v.z), f32_to_bf16bits(v.w) };
    ((u16x4*)dst)[i] = o;
}

// ------------------------------------------- weight transpose fp32(K,N)->bf16(N,K)
__global__ void transpose_wT(const float* __restrict__ src, u16* __restrict__ dst,
                             int N, int dstStride) {
    __shared__ float tile[32][129];
    const int n0 = blockIdx.x * 128, k0 = blockIdx.y * 32;
    const int tx = threadIdx.x, ty = threadIdx.y;      // (32, 8)
#pragma unroll
    for (int j = 0; j < 4; ++j)
#pragma unroll
        for (int i = 0; i < 4; ++i)
            tile[ty + 8*j][tx + 32*i] = src[(size_t)(k0 + ty + 8*j) * N + n0 + tx + 32*i];
    __syncthreads();
    const int tid = ty * 32 + tx;
    const int c = tid & 15, nl0 = tid >> 4;
#pragma unroll
    for (int s = 0; s < 8; ++s) {
        const int nl = nl0 + s * 16;
        const u32 pk = (u32)f32_to_bf16bits(tile[2*c][nl])
                     | ((u32)f32_to_bf16bits(tile[2*c + 1][nl]) << 16);
        *(u32*)&dst[(size_t)(n0 + nl) * dstStride + k0 + 2*c] = pk;
    }
}

// ------------------------------------------- V transpose bf16 (s,dcol)->(dcol,s)
__global__ void transpose_v(const u16* __restrict__ qkv, u16* __restrict__ vT) {
    __shared__ u16 tile[32][34];
    const int s0 = blockIdx.x * 32, n0 = blockIdx.y * 32;
    const int tx = threadIdx.x, ty = threadIdx.y;
#pragma unroll
    for (int i = 0; i < 4; ++i)
        tile[ty + i*8][tx] = qkv[(size_t)(s0 + ty + i*8) * 6144 + 5120 + n0 + tx];
    __syncthreads();
#pragma unroll
    for (int i = 0; i < 4; ++i)
        vT[(size_t)(n0 + ty + i*8) * 2048 + s0 + tx] = tile[tx][ty + i*8];
}

// ---------------------------------------------------------------- RoPE in place
__global__ void rope_kernel(u32* __restrict__ qkv, const float* __restrict__ cosp,
                            const float* __restrict__ sinp) {
    const int s = blockIdx.x;
    const int h = blockIdx.y * 4 + (threadIdx.x >> 6);
    const int p = threadIdx.x & 63;
    const size_t off = ((size_t)s * 6144 + h * 128) >> 1;
    const u32 packed = qkv[off + p];
    const float c  = cosp[s*64 + p], sn = sinp[s*64 + p];
    const float t1 = bf16bits_to_f32((u16)(packed & 0xffffu));
    const float t2 = bf16bits_to_f32((u16)(packed >> 16));
    const float o1 = t1 * c - t2 * sn;
    const float o2 = t1 * sn + t2 * c;
    qkv[off + p] = (u32)f32_to_bf16bits(o1) | ((u32)f32_to_bf16bits(o2) << 16);
}

// ---------------------------------------------------------------- qkv GEMM
// C[2048,6144] = A[2048,4096] * B[6144,4096]^T.  BM=128, BN=384, BK=64.
// Grid 256 (full chip).  8 waves (2m x 4n); wave = 64r x 96c (4m x 6n frags).
// Phases sliced by K-half (dk) to balance LDS reads: per ktile
//   p0: rd B[dk0](6)+A01[dk0](2) -> MFMA (m01,dk0)=12
//   p1: rd B[dk1](6)+A23[dk0](2) -> MFMA (m23,dk0)=12   (B reads done by p1)
//   p2: rd A01[dk1](2)           -> MFMA (m01,dk1)=12
//   p3: rd A23[dk1](2)           -> MFMA (m23,dk1)=12
// Staging skeleton identical to validated round-6 kernel (A at p0/p1/p4/p5,
// B at p2/p3/p6/p7, vmcnt(6) at p3/p7, vmcnt(0) on guarded tail).
#define Q_RD_BF(d, dk) do { _Pragma("unroll")                                  \
    for (int ni = 0; ni < 6; ++ni) {                                           \
        const char* bb = sm + 32768 + ((d)*2 + bh)*24576                       \
                       + ((wn&1)*96 + ni*16 + c0)*128;                         \
        bfr[ni][dk] = *(const bf16x8*)(bb + ((((dk)*4 + g) ^ (c0&7)) * 16));   \
    } } while (0)

#define Q_RD_AF(dst, d, mh, dk) do { _Pragma("unroll")                         \
    for (int mi = 0; mi < 2; ++mi) {                                           \
        const char* ab = sm + ((d)*2 + wm)*8192 + (((mh)*2+mi)*16 + c0)*128;   \
        dst[mi] = *(const bf16x8*)(ab + ((((dk)*4 + g) ^ (c0&7)) * 16));       \
    } } while (0)

#define Q_MFMA(MH, DK, AFR) do {                                               \
    __builtin_amdgcn_s_barrier();                                              \
    asm volatile("s_waitcnt lgkmcnt(0)" ::: "memory");                         \
    __builtin_amdgcn_sched_barrier(0);                                         \
    __builtin_amdgcn_s_setprio(1);                                             \
    _Pragma("unroll") for (int mi = 0; mi < 2; ++mi)                           \
    _Pragma("unroll") for (int ni = 0; ni < 6; ++ni)                           \
        acc[(MH)*2+mi][ni] = __builtin_amdgcn_mfma_f32_16x16x32_bf16(          \
            AFR[mi], bfr[ni][DK], acc[(MH)*2+mi][ni], 0,0,0);                  \
    __builtin_amdgcn_s_setprio(0); } while (0)

__global__ __launch_bounds__(512, 2) void gemm_qkv(
    const u16* __restrict__ A, const u16* __restrict__ B, u16* __restrict__ C,
    const int N, const int K) {
    __shared__ __align__(16) char sm[131072];
    const int tid = threadIdx.x;
    const int w = tid >> 6, l = tid & 63;
    const int wm = w >> 2, wn = w & 3, bh = wn >> 1;
    const int g = l >> 4, c0 = l & 15;
    const int bm = blockIdx.x >> 4, bn = blockIdx.x & 15;

    const int srow   = w*8 + (l >> 3);
    const int schunk = (l & 7) ^ (l >> 3);
    const u16* Abase = A + (size_t)(bm*128 + srow) * K + schunk*8;
    const u16* Bbase = B + (size_t)(bn*384 + srow) * K + schunk*8;

    f32x4 acc[4][6] = {};
    bf16x8 bfr[6][2], afa[2], afb[2];

    auto stageA = [&](int kt, int d, int h) {
        async_copy16(sm + (d*2 + h)*8192 + (w*8)*128,
                     Abase + (size_t)h*64*K + kt*64);
    };
    auto stageB = [&](int kt, int d, int h) {
        char* dst = sm + 32768 + (d*2 + h)*24576 + (w*8)*128;
        const u16* src = Bbase + (size_t)h*192*K + kt*64;
#pragma unroll
        for (int r = 0; r < 3; ++r)
            async_copy16(dst + r*8192, src + (size_t)r*64*K);
    };

    const int nkt = K >> 6;    // 64

    // prologue: ktile0 full + ktile1 B halves; retire ktile0, keep B1 in flight
    stageB(0, 0, 0); stageB(0, 0, 1);
    stageA(0, 0, 0); stageA(0, 0, 1);
    stageB(1, 1, 0); stageB(1, 1, 1);
    VMC6();
    __builtin_amdgcn_s_barrier();

    for (int t = 0; t < nkt; t += 2) {
        const int tb = t + 1, tc = t + 2, td = t + 3;
        // ---- ktile t (buf0) ----
        Q_RD_BF(0, 0); Q_RD_AF(afa, 0, 0, 0); stageA(tb, 1, 0);
        Q_MFMA(0, 0, afa); ENDBAR();
        Q_RD_BF(0, 1); Q_RD_AF(afb, 0, 1, 0); stageA(tb, 1, 1);
        Q_MFMA(1, 0, afb); ENDBAR();
        Q_RD_AF(afa, 0, 0, 1); if (tc < nkt) stageB(tc, 0, 0);
        Q_MFMA(0, 1, afa); ENDBAR();
        Q_RD_AF(afb, 0, 1, 1);
        if (tc < nkt) { stageB(tc, 0, 1); Q_MFMA(1, 1, afb); VMC6(); }
        else          { Q_MFMA(1, 1, afb); VMC0(); }
        ENDBAR();
        // ---- ktile t+1 (buf1) ----
        Q_RD_BF(1, 0); Q_RD_AF(afa, 1, 0, 0); if (tc < nkt) stageA(tc, 0, 0);
        Q_MFMA(0, 0, afa); ENDBAR();
        Q_RD_BF(1, 1); Q_RD_AF(afb, 1, 1, 0); if (tc < nkt) stageA(tc, 0, 1);
        Q_MFMA(1, 0, afb); ENDBAR();
        Q_RD_AF(afa, 1, 0, 1); if (td < nkt) stageB(td, 1, 0);
        Q_MFMA(0, 1, afa); ENDBAR();
        Q_RD_AF(afb, 1, 1, 1);
        if (td < nkt) { stageB(td, 1, 1); Q_MFMA(1, 1, afb); VMC6(); }
        else          { Q_MFMA(1, 1, afb); VMC0(); }
        ENDBAR();
    }
    VMC0();  // drain before LDS dealloc

#pragma unroll
    for (int m = 0; m < 4; ++m)
#pragma unroll
        for (int n = 0; n < 6; ++n) {
            const int row = bm*128 + wm*64 + m*16 + g*4;
            const int col = bn*384 + wn*96 + n*16 + c0;
#pragma unroll
            for (int r = 0; r < 4; ++r)
                C[(size_t)(row + r) * N + col] = f32_to_bf16bits(acc[m][n][r]);
        }
}
#undef Q_RD_BF
#undef Q_RD_AF
#undef Q_MFMA

// ---------------------------------------------------------------- out-proj GEMM
// C[2048,4096](f32) = A[2048,4096] * B[4096,4096]^T.  BM=128, BN=256, BK=64.
// Grid 256.  8 waves (2m x 4n); wave = 64r x 64c (4m x 4n frags).
// TRIPLE-buffered LDS (3 x 48KB); 2 phases/ktile sliced by dk:
//   each phase: rd A[dk](4) + B[dk](4) = 8 reads -> 16 MFMA.  Balanced 8/8.
// Stage ktile t+2 into buf (t+2)%3; vmcnt(6) once per ktile.
#define O_RD(b, dk) do { _Pragma("unroll")                                     \
    for (int mi = 0; mi < 4; ++mi) {                                           \
        const char* ab = sm + (b)*49152 + (wm*64 + mi*16 + c0)*128;            \
        af[mi] = *(const bf16x8*)(ab + ((((dk)*4+g) ^ (c0&7)) * 16));          \
    }                                                                          \
    _Pragma("unroll")                                                          \
    for (int nj = 0; nj < 4; ++nj) {                                           \
        const char* bb = sm + (b)*49152 + 16384 + (wn*64 + nj*16 + c0)*128;    \
        bfv[nj] = *(const bf16x8*)(bb + ((((dk)*4+g) ^ (c0&7)) * 16));         \
    } } while (0)

#define O_MFMA() do {                                                          \
    __builtin_amdgcn_s_barrier();                                              \
    asm volatile("s_waitcnt lgkmcnt(0)" ::: "memory");                         \
    __builtin_amdgcn_sched_barrier(0);                                         \
    __builtin_amdgcn_s_setprio(1);                                             \
    _Pragma("unroll") for (int mi = 0; mi < 4; ++mi)                           \
    _Pragma("unroll") for (int nj = 0; nj < 4; ++nj)                           \
        acc[mi][nj] = __builtin_amdgcn_mfma_f32_16x16x32_bf16(                 \
            af[mi], bfv[nj], acc[mi][nj], 0,0,0);                              \
    __builtin_amdgcn_s_setprio(0); } while (0)

__global__ __launch_bounds__(512, 2) void gemm_out(
    const u16* __restrict__ A, const u16* __restrict__ B, float* __restrict__ C,
    const int N, const int K) {
    __shared__ __align__(16) char sm[147456];
    const int tid = threadIdx.x;
    const int w = tid >> 6, l = tid & 63;
    const int wm = w >> 2, wn = w & 3;
    const int g = l >> 4, c0 = l & 15;
    const int bm = blockIdx.x >> 4, bn = blockIdx.x & 15;

    const int srow   = w*8 + (l >> 3);
    const int schunk = (l & 7) ^ (l >> 3);
    const u16* Abase = A + (size_t)(bm*128 + srow) * K + schunk*8;
    const u16* Bbase = B + (size_t)(bn*256 + srow) * K + schunk*8;

    f32x4 acc[4][4] = {};
    bf16x8 af[4], bfv[4];

    auto stage_p0 = [&](int kt, int b) {   // A rows 0-63, B rows 0-127
        char* base = sm + b*49152 + (w*8)*128;
        async_copy16(base,                 Abase + kt*64);
        async_copy16(base + 16384,         Bbase + kt*64);
        async_copy16(base + 16384 + 8192,  Bbase + (size_t)64*K + kt*64);
    };
    auto stage_p1 = [&](int kt, int b) {   // A rows 64-127, B rows 128-255
        char* base = sm + b*49152 + (w*8)*128;
        async_copy16(base + 8192,          Abase + (size_t)64*K  + kt*64);
        async_copy16(base + 16384 + 16384, Bbase + (size_t)128*K + kt*64);
        async_copy16(base + 16384 + 24576, Bbase + (size_t)192*K + kt*64);
    };

    const int nkt = K >> 6;    // 64

    // prologue: ktiles 0,1 into bufs 0,1; retire ktile0, keep ktile1 in flight
    stage_p0(0, 0); stage_p1(0, 0);
    stage_p0(1, 1); stage_p1(1, 1);
    VMC6();
    __builtin_amdgcn_s_barrier();

    int bc = 0;
    for (int t = 0; t < nkt; ++t) {
        const int b2 = (bc == 0) ? 2 : bc - 1;        // (bc+2)%3
        const bool st = (t + 2) < nkt;
        // phase 0: dk0 slice; stage half of ktile t+2
        O_RD(bc, 0);
        if (st) stage_p0(t + 2, b2);
        O_MFMA(); ENDBAR();
        // phase 1: dk1 slice; stage rest of ktile t+2; retire ktile t+1's stages
        O_RD(bc, 1);
        if (st) { stage_p1(t + 2, b2); O_MFMA(); VMC6(); }
        else    { O_MFMA(); VMC0(); }
        ENDBAR();
        bc = (bc == 2) ? 0 : bc + 1;
    }
    VMC0();  // drain before LDS dealloc

#pragma unroll
    for (int m = 0; m < 4; ++m)
#pragma unroll
        for (int n = 0; n < 4; ++n) {
            const int row = bm*128 + wm*64 + m*16 + g*4;
            const int col = bn*256 + wn*64 + n*16 + c0;
#pragma unroll
            for (int r = 0; r < 4; ++r)
                C[(size_t)(row + r) * N + col] = acc[m][n][r];
        }
}
#undef O_RD
#undef O_MFMA

// ---------------------------------------------------------------- flash attention
// (unchanged — validated rounds 2-6)
__global__ __launch_bounds__(256, 2) void attn_kernel(
    const u16* __restrict__ qkv, const u16* __restrict__ vT, u16* __restrict__ outp) {
    __shared__ __align__(16) char lds[65536];
    const int tid = threadIdx.x;
    const int w = tid >> 6, l = tid & 63;
    const int g = l >> 4, c0 = l & 15;
    const int qt = (blockIdx.y < 16) ? blockIdx.x : (15 - (int)blockIdx.x);
    const int h = blockIdx.y;
    const int kvh = h >> 2;
    const int q0g = qt * 128;
    const int qrow0 = q0g + w * 32;

    const int srK = w*4 + g,        scK = c0 ^ srK;
    const int srV = w*8 + (l >> 3), scV = (l & 7) ^ (l >> 3);

#pragma unroll
    for (int i = 0; i < 8; ++i)
        async_copy16(lds + (i*16 + w*4) * 256,
                     qkv + (size_t)(q0g + i*16 + srK) * 6144 + h*128 + scK*8);
    __syncthreads();

#pragma unroll
    for (int i = 0; i < 4; ++i)
        async_copy16(lds + 32768 + (i*16 + w*4) * 256,
                     qkv + (size_t)(i*16 + srK) * 6144 + 4096 + kvh*128 + scK*8);
#pragma unroll
    for (int i = 0; i < 4; ++i)
        async_copy16(lds + 49152 + (i*32 + w*8) * 128,
                     vT + (size_t)(kvh*128 + i*32 + srV) * 2048 + scV*8);

    bf16x8 qf[2][4];
#pragma unroll
    for (int i = 0; i < 2; ++i)
#pragma unroll
        for (int dks = 0; dks < 4; ++dks) {
            const int row = w*32 + i*16 + c0;
            qf[i][dks] = *(const bf16x8*)(lds + row*256 + (((dks*4 + g) ^ c0) * 16));
        }
    __syncthreads();

    f32x4 o[2][8] = {};
    float lsum[2] = {0.f, 0.f};
    const int ntiles = 2*qt + 2;
    const float SC2 = 0.08838834764831845f * 1.4426950408889634f;

    for (int kt = 0; kt < ntiles; ++kt) {
        const int cur = kt & 1;
        const char* kb = lds + (cur ? 0 : 32768);
        const char* vb = lds + (cur ? 16384 : 49152);
        if (kt + 1 < ntiles) {
            char* kbn = lds + ((cur ^ 1) ? 0 : 32768);
            char* vbn = lds + ((cur ^ 1) ? 16384 : 49152);
#pragma unroll
            for (int i = 0; i < 4; ++i)
                async_copy16(kbn + (i*16 + w*4) * 256,
                             qkv + (size_t)((kt+1)*64 + i*16 + srK) * 6144 + 4096 + kvh*128 + scK*8);
#pragma unroll
            for (int i = 0; i < 4; ++i)
                async_copy16(vbn + (i*32 + w*8) * 128,
                             vT + (size_t)(kvh*128 + i*32 + srV) * 2048 + (kt+1)*64 + scV*8);
        }

        if (kt*64 <= qrow0 + 31) {
            f32x4 st[2][4] = {};
            __builtin_amdgcn_s_setprio(1);
#pragma unroll
            for (int dks = 0; dks < 4; ++dks) {
                bf16x8 kf[4];
#pragma unroll
                for (int j = 0; j < 4; ++j) {
                    const int row = j*16 + c0;
                    kf[j] = *(const bf16x8*)(kb + row*256 + (((dks*4 + g) ^ c0) * 16));
                }
#pragma unroll
                for (int i = 0; i < 2; ++i)
#pragma unroll
                    for (int j = 0; j < 4; ++j)
                        st[i][j] = __builtin_amdgcn_mfma_f32_16x16x32_bf16(
                            kf[j], qf[i][dks], st[i][j], 0, 0, 0);
            }
            __builtin_amdgcn_s_setprio(0);

            const bool diag = (kt*64 + 63) > qrow0;
            u32 pk[2][4][2];
#pragma unroll
            for (int i = 0; i < 2; ++i) {
                float rowsum = 0.f;
#pragma unroll
                for (int j = 0; j < 4; ++j) {
#pragma unroll
                    for (int r = 0; r < 4; ++r) {
                        float p = exp2f(st[i][j][r] * SC2);
                        if (diag) {
                            const int kgl = kt*64 + j*16 + g*4 + r;
                            const int qgl = qrow0 + i*16 + c0;
                            if (kgl > qgl) p = 0.f;
                        }
                        st[i][j][r] = p;
                        rowsum += p;
                    }
                    pk[i][j][0] = cvt_pk_bf16(st[i][j][0], st[i][j][1]);
                    pk[i][j][1] = cvt_pk_bf16(st[i][j][2], st[i][j][3]);
                }
                rowsum += __shfl_xor(rowsum, 16);
                rowsum += __shfl_xor(rowsum, 32);
                lsum[i] += rowsum;
            }

#pragma unroll
            for (int dks = 0; dks < 2; ++dks) {
                bf16x8 pf[2];
#pragma unroll
                for (int i = 0; i < 2; ++i) {
                    union { u32 u[4]; bf16x8 v; } pu;
                    pu.u[0] = pk[i][2*dks][0];   pu.u[1] = pk[i][2*dks][1];
                    pu.u[2] = pk[i][2*dks+1][0]; pu.u[3] = pk[i][2*dks+1][1];
                    pf[i] = pu.v;
                }
                __builtin_amdgcn_s_setprio(1);
#pragma unroll
                for (int dj = 0; dj < 8; ++dj) {
                    const int row = dj*16 + c0;
                    const int cg0 = (4*dks + (g >> 1)) ^ (row & 7);
                    const int cg1 = (4*dks + (g >> 1) + 2) ^ (row & 7);
                    union { struct { bf16x4 lo, hi; } p; bf16x8 v; } vu;
                    vu.p.lo = *(const bf16x4*)(vb + row*128 + cg0*16 + 8*(g & 1));
                    vu.p.hi = *(const bf16x4*)(vb + row*128 + cg1*16 + 8*(g & 1));
#pragma unroll
                    for (int i = 0; i < 2; ++i)
                        o[i][dj] = __builtin_amdgcn_mfma_f32_16x16x32_bf16(
                            vu.v, pf[i], o[i][dj], 0, 0, 0);
                }
                __builtin_amdgcn_s_setprio(0);
            }
        }
        __syncthreads();
    }

#pragma unroll
    for (int i = 0; i < 2; ++i) {
        const float rcp = 1.0f / lsum[i];
        const int qg = qrow0 + i*16 + c0;
#pragma unroll
        for (int dj = 0; dj < 8; ++dj) {
            u16x4 ov = { f32_to_bf16bits(o[i][dj][0] * rcp),
                         f32_to_bf16bits(o[i][dj][1] * rcp),
                         f32_to_bf16bits(o[i][dj][2] * rcp),
                         f32_to_bf16bits(o[i][dj][3] * rcp) };
            *(u16x4*)(outp + (size_t)qg * 4096 + h*128 + dj*16 + g*4) = ov;
        }
    }
}

// ---------------------------------------------------------------- launcher
extern "C" void kernel_launch(void* const* d_in, const int* in_sizes, int n_in,
                              void* d_out, int out_size, void* d_ws, size_t ws_size,
                              hipStream_t stream) {
    const float* x    = (const float*)d_in[0];
    const float* wq   = (const float*)d_in[1];
    const float* wk   = (const float*)d_in[2];
    const float* wv   = (const float*)d_in[3];
    const float* wo   = (const float*)d_in[4];
    const float* cosp = (const float*)d_in[5];
    const float* sinp = (const float*)d_in[6];
    // d_in[7] = mask — causality applied analytically in attn_kernel.

    char* ws = (char*)d_ws;
    u16* xb    = (u16*)(ws);                       //  16.8 MB  x bf16 (2048x4096)
    u16* wqkvT = (u16*)(ws + 16777216);            //  50.3 MB  [wq|wk|wv]^T (6144x4096)
    u16* woT   = (u16*)(ws + 67108864);            //  33.6 MB  wo^T (4096x4096)
    u16* qkv   = (u16*)(ws + 100663296);           //  25.2 MB  qkv (2048x6144)
    u16* vTb   = (u16*)(ws + 125829120);           //   4.2 MB  v^T (1024x2048)
    u16* attn  = (u16*)(ws + 130023424);           //  16.8 MB  attn out (2048x4096)

    dim3 tb(32, 8);
    convert_f32_bf16<<<8192, 256, 0, stream>>>(x, xb, 2097152);
    transpose_wT<<<dim3(32, 128), tb, 0, stream>>>(wq, wqkvT, 4096, 4096);
    transpose_wT<<<dim3(8, 128),  tb, 0, stream>>>(wk, wqkvT + (size_t)4096*4096, 1024, 4096);
    transpose_wT<<<dim3(8, 128),  tb, 0, stream>>>(wv, wqkvT + (size_t)5120*4096, 1024, 4096);
    transpose_wT<<<dim3(32, 128), tb, 0, stream>>>(wo, woT, 4096, 4096);

    gemm_qkv<<<256, 512, 0, stream>>>(xb, wqkvT, qkv, 6144, 4096);
    rope_kernel<<<dim3(2048, 10), 256, 0, stream>>>((u32*)qkv, cosp, sinp);
    transpose_v<<<dim3(64, 32), tb, 0, stream>>>(qkv, vTb);
    attn_kernel<<<dim3(16, 32), 256, 0, stream>>>(qkv, vTb, attn);
    gemm_out<<<256, 512, 0, stream>>>(attn, woT, (float*)d_out, 4096, 4096);
}

// Round 8
// 314.516 us; speedup vs baseline: 1.0097x; 1.0018x over previous
//
#include <hip/hip_runtime.h>
#include <hip/hip_bf16.h>

typedef unsigned short u16;
typedef unsigned int   u32;
typedef __attribute__((ext_vector_type(8))) short bf16x8;
typedef __attribute__((ext_vector_type(4))) short bf16x4;
typedef __attribute__((ext_vector_type(4))) float f32x4;
typedef __attribute__((ext_vector_type(4))) unsigned short u16x4;

__device__ __forceinline__ u16 f32_to_bf16bits(float f) {
    u32 x = __float_as_uint(f);
    u32 r = (x + 0x7fffu + ((x >> 16) & 1u)) >> 16;   // RNE
    return (u16)r;
}
__device__ __forceinline__ float bf16bits_to_f32(u16 u) {
    return __uint_as_float(((u32)u) << 16);
}
__device__ __forceinline__ u32 cvt_pk_bf16(float lo, float hi) {
    u32 r;
    asm("v_cvt_pk_bf16_f32 %0, %1, %2" : "=v"(r) : "v"(lo), "v"(hi));
    return r;
}

// async global->LDS, 16B per lane. LDS dest is wave-uniform base + lane*16.
__device__ __forceinline__ void async_copy16(void* lds, const void* g) {
    __builtin_amdgcn_global_load_lds(
        (__attribute__((address_space(1))) void*)(g),
        (__attribute__((address_space(3))) void*)(lds), 16, 0, 0);
}

#define VMC6() asm volatile("s_waitcnt vmcnt(6)" ::: "memory")
#define VMC0() asm volatile("s_waitcnt vmcnt(0)" ::: "memory")
#define ENDBAR() __builtin_amdgcn_s_barrier()

// ---------------------------------------------------------------- convert x
__global__ void convert_f32_bf16(const float* __restrict__ src, u16* __restrict__ dst, int n4) {
    const int i = blockIdx.x * 256 + threadIdx.x;
    if (i >= n4) return;
    const float4 v = ((const float4*)src)[i];
    u16x4 o = { f32_to_bf16bits(v.x), f32_to_bf16bits(v.y),
                f32_to_bf16bits(v.z), f32_to_bf16bits(v.w) };
    ((u16x4*)dst)[i] = o;
}

// ------------------------------------------- weight transpose fp32(K,N)->bf16(N,K)
__global__ void transpose_wT(const float* __restrict__ src, u16* __restrict__ dst,
                             int N, int dstStride) {
    __shared__ float tile[32][129];
    const int n0 = blockIdx.x * 128, k0 = blockIdx.y * 32;
    const int tx = threadIdx.x, ty = threadIdx.y;      // (32, 8)
#pragma unroll
    for (int j = 0; j < 4; ++j)
#pragma unroll
        for (int i = 0; i < 4; ++i)
            tile[ty + 8*j][tx + 32*i] = src[(size_t)(k0 + ty + 8*j) * N + n0 + tx + 32*i];
    __syncthreads();
    const int tid = ty * 32 + tx;
    const int c = tid & 15, nl0 = tid >> 4;
#pragma unroll
    for (int s = 0; s < 8; ++s) {
        const int nl = nl0 + s * 16;
        const u32 pk = (u32)f32_to_bf16bits(tile[2*c][nl])
                     | ((u32)f32_to_bf16bits(tile[2*c + 1][nl]) << 16);
        *(u32*)&dst[(size_t)(n0 + nl) * dstStride + k0 + 2*c] = pk;
    }
}

// ------------------------------------------- V transpose bf16 (s,dcol)->(dcol,s)
__global__ void transpose_v(const u16* __restrict__ qkv, u16* __restrict__ vT) {
    __shared__ u16 tile[32][34];
    const int s0 = blockIdx.x * 32, n0 = blockIdx.y * 32;
    const int tx = threadIdx.x, ty = threadIdx.y;
#pragma unroll
    for (int i = 0; i < 4; ++i)
        tile[ty + i*8][tx] = qkv[(size_t)(s0 + ty + i*8) * 6144 + 5120 + n0 + tx];
    __syncthreads();
#pragma unroll
    for (int i = 0; i < 4; ++i)
        vT[(size_t)(n0 + ty + i*8) * 2048 + s0 + tx] = tile[tx][ty + i*8];
}

// ---------------------------------------------------------------- RoPE in place
__global__ void rope_kernel(u32* __restrict__ qkv, const float* __restrict__ cosp,
                            const float* __restrict__ sinp) {
    const int s = blockIdx.x;
    const int h = blockIdx.y * 4 + (threadIdx.x >> 6);
    const int p = threadIdx.x & 63;
    const size_t off = ((size_t)s * 6144 + h * 128) >> 1;
    const u32 packed = qkv[off + p];
    const float c  = cosp[s*64 + p], sn = sinp[s*64 + p];
    const float t1 = bf16bits_to_f32((u16)(packed & 0xffffu));
    const float t2 = bf16bits_to_f32((u16)(packed >> 16));
    const float o1 = t1 * c - t2 * sn;
    const float o2 = t1 * sn + t2 * c;
    qkv[off + p] = (u32)f32_to_bf16bits(o1) | ((u32)f32_to_bf16bits(o2) << 16);
}

// ---------------------------------------------------------------- qkv GEMM
// C[2048,6144] = A[2048,4096] * B[6144,4096]^T.  BM=128, BN=384, BK=64.
// Grid 256 (full chip).  8 waves (2m x 4n); wave = 64r x 96c (4m x 6n frags).
// Phases sliced by K-half (dk) to balance LDS reads: per ktile
//   p0: rd B[dk0](6)+A01[dk0](2) -> MFMA (m01,dk0)=12
//   p1: rd B[dk1](6)+A23[dk0](2) -> MFMA (m23,dk0)=12   (B reads done by p1)
//   p2: rd A01[dk1](2)           -> MFMA (m01,dk1)=12
//   p3: rd A23[dk1](2)           -> MFMA (m23,dk1)=12
// Staging skeleton identical to validated round-6 kernel (A at p0/p1/p4/p5,
// B at p2/p3/p6/p7, vmcnt(6) at p3/p7, vmcnt(0) on guarded tail).
#define Q_RD_BF(d, dk) do { _Pragma("unroll")                                  \
    for (int ni = 0; ni < 6; ++ni) {                                           \
        const char* bb = sm + 32768 + ((d)*2 + bh)*24576                       \
                       + ((wn&1)*96 + ni*16 + c0)*128;                         \
        bfr[ni][dk] = *(const bf16x8*)(bb + ((((dk)*4 + g) ^ (c0&7)) * 16));   \
    } } while (0)

#define Q_RD_AF(dst, d, mh, dk) do { _Pragma("unroll")                         \
    for (int mi = 0; mi < 2; ++mi) {                                           \
        const char* ab = sm + ((d)*2 + wm)*8192 + (((mh)*2+mi)*16 + c0)*128;   \
        dst[mi] = *(const bf16x8*)(ab + ((((dk)*4 + g) ^ (c0&7)) * 16));       \
    } } while (0)

#define Q_MFMA(MH, DK, AFR) do {                                               \
    __builtin_amdgcn_s_barrier();                                              \
    asm volatile("s_waitcnt lgkmcnt(0)" ::: "memory");                         \
    __builtin_amdgcn_sched_barrier(0);                                         \
    __builtin_amdgcn_s_setprio(1);                                             \
    _Pragma("unroll") for (int mi = 0; mi < 2; ++mi)                           \
    _Pragma("unroll") for (int ni = 0; ni < 6; ++ni)                           \
        acc[(MH)*2+mi][ni] = __builtin_amdgcn_mfma_f32_16x16x32_bf16(          \
            AFR[mi], bfr[ni][DK], acc[(MH)*2+mi][ni], 0,0,0);                  \
    __builtin_amdgcn_s_setprio(0); } while (0)

__global__ __launch_bounds__(512, 2) void gemm_qkv(
    const u16* __restrict__ A, const u16* __restrict__ B, u16* __restrict__ C,
    const int N, const int K) {
    __shared__ __align__(16) char sm[131072];
    const int tid = threadIdx.x;
    const int w = tid >> 6, l = tid & 63;
    const int wm = w >> 2, wn = w & 3, bh = wn >> 1;
    const int g = l >> 4, c0 = l & 15;
    const int bm = blockIdx.x >> 4, bn = blockIdx.x & 15;

    const int srow   = w*8 + (l >> 3);
    const int schunk = (l & 7) ^ (l >> 3);
    const u16* Abase = A + (size_t)(bm*128 + srow) * K + schunk*8;
    const u16* Bbase = B + (size_t)(bn*384 + srow) * K + schunk*8;

    f32x4 acc[4][6] = {};
    bf16x8 bfr[6][2], afa[2], afb[2];

    auto stageA = [&](int kt, int d, int h) {
        async_copy16(sm + (d*2 + h)*8192 + (w*8)*128,
                     Abase + (size_t)h*64*K + kt*64);
    };
    auto stageB = [&](int kt, int d, int h) {
        char* dst = sm + 32768 + (d*2 + h)*24576 + (w*8)*128;
        const u16* src = Bbase + (size_t)h*192*K + kt*64;
#pragma unroll
        for (int r = 0; r < 3; ++r)
            async_copy16(dst + r*8192, src + (size_t)r*64*K);
    };

    const int nkt = K >> 6;    // 64

    // prologue: ktile0 full + ktile1 B halves; retire ktile0, keep B1 in flight
    stageB(0, 0, 0); stageB(0, 0, 1);
    stageA(0, 0, 0); stageA(0, 0, 1);
    stageB(1, 1, 0); stageB(1, 1, 1);
    VMC6();
    __builtin_amdgcn_s_barrier();

    for (int t = 0; t < nkt; t += 2) {
        const int tb = t + 1, tc = t + 2, td = t + 3;
        // ---- ktile t (buf0) ----
        Q_RD_BF(0, 0); Q_RD_AF(afa, 0, 0, 0); stageA(tb, 1, 0);
        Q_MFMA(0, 0, afa); ENDBAR();
        Q_RD_BF(0, 1); Q_RD_AF(afb, 0, 1, 0); stageA(tb, 1, 1);
        Q_MFMA(1, 0, afb); ENDBAR();
        Q_RD_AF(afa, 0, 0, 1); if (tc < nkt) stageB(tc, 0, 0);
        Q_MFMA(0, 1, afa); ENDBAR();
        Q_RD_AF(afb, 0, 1, 1);
        if (tc < nkt) { stageB(tc, 0, 1); Q_MFMA(1, 1, afb); VMC6(); }
        else          { Q_MFMA(1, 1, afb); VMC0(); }
        ENDBAR();
        // ---- ktile t+1 (buf1) ----
        Q_RD_BF(1, 0); Q_RD_AF(afa, 1, 0, 0); if (tc < nkt) stageA(tc, 0, 0);
        Q_MFMA(0, 0, afa); ENDBAR();
        Q_RD_BF(1, 1); Q_RD_AF(afb, 1, 1, 0); if (tc < nkt) stageA(tc, 0, 1);
        Q_MFMA(1, 0, afb); ENDBAR();
        Q_RD_AF(afa, 1, 0, 1); if (td < nkt) stageB(td, 1, 0);
        Q_MFMA(0, 1, afa); ENDBAR();
        Q_RD_AF(afb, 1, 1, 1);
        if (td < nkt) { stageB(td, 1, 1); Q_MFMA(1, 1, afb); VMC6(); }
        else          { Q_MFMA(1, 1, afb); VMC0(); }
        ENDBAR();
    }
    VMC0();  // drain before LDS dealloc

#pragma unroll
    for (int m = 0; m < 4; ++m)
#pragma unroll
        for (int n = 0; n < 6; ++n) {
            const int row = bm*128 + wm*64 + m*16 + g*4;
            const int col = bn*384 + wn*96 + n*16 + c0;
#pragma unroll
            for (int r = 0; r < 4; ++r)
                C[(size_t)(row + r) * N + col] = f32_to_bf16bits(acc[m][n][r]);
        }
}
#undef Q_RD_BF
#undef Q_RD_AF
#undef Q_MFMA

// ---------------------------------------------------------------- out-proj GEMM
// C[2048,4096](f32) = A[2048,4096] * B[4096,4096]^T.  BM=128, BN=256, BK=64.
// Grid 256.  8 waves (2m x 4n); wave = 64r x 64c (4m x 4n frags).
// TRIPLE-buffered LDS (3 x 48KB); 2 phases/ktile sliced by dk:
//   each phase: rd A[dk](4) + B[dk](4) = 8 reads -> 16 MFMA.  Balanced 8/8.
// Stage ktile t+2 into buf (t+2)%3; vmcnt(6) once per ktile.
#define O_RD(b, dk) do { _Pragma("unroll")                                     \
    for (int mi = 0; mi < 4; ++mi) {                                           \
        const char* ab = sm + (b)*49152 + (wm*64 + mi*16 + c0)*128;            \
        af[mi] = *(const bf16x8*)(ab + ((((dk)*4+g) ^ (c0&7)) * 16));          \
    }                                                                          \
    _Pragma("unroll")                                                          \
    for (int nj = 0; nj < 4; ++nj) {                                           \
        const char* bb = sm + (b)*49152 + 16384 + (wn*64 + nj*16 + c0)*128;    \
        bfv[nj] = *(const bf16x8*)(bb + ((((dk)*4+g) ^ (c0&7)) * 16));         \
    } } while (0)

#define O_MFMA() do {                                                          \
    __builtin_amdgcn_s_barrier();                                              \
    asm volatile("s_waitcnt lgkmcnt(0)" ::: "memory");                         \
    __builtin_amdgcn_sched_barrier(0);                                         \
    __builtin_amdgcn_s_setprio(1);                                             \
    _Pragma("unroll") for (int mi = 0; mi < 4; ++mi)                           \
    _Pragma("unroll") for (int nj = 0; nj < 4; ++nj)                           \
        acc[mi][nj] = __builtin_amdgcn_mfma_f32_16x16x32_bf16(                 \
            af[mi], bfv[nj], acc[mi][nj], 0,0,0);                              \
    __builtin_amdgcn_s_setprio(0); } while (0)

__global__ __launch_bounds__(512, 2) void gemm_out(
    const u16* __restrict__ A, const u16* __restrict__ B, float* __restrict__ C,
    const int N, const int K) {
    __shared__ __align__(16) char sm[147456];
    const int tid = threadIdx.x;
    const int w = tid >> 6, l = tid & 63;
    const int wm = w >> 2, wn = w & 3;
    const int g = l >> 4, c0 = l & 15;
    const int bm = blockIdx.x >> 4, bn = blockIdx.x & 15;

    const int srow   = w*8 + (l >> 3);
    const int schunk = (l & 7) ^ (l >> 3);
    const u16* Abase = A + (size_t)(bm*128 + srow) * K + schunk*8;
    const u16* Bbase = B + (size_t)(bn*256 + srow) * K + schunk*8;

    f32x4 acc[4][4] = {};
    bf16x8 af[4], bfv[4];

    auto stage_p0 = [&](int kt, int b) {   // A rows 0-63, B rows 0-127
        char* base = sm + b*49152 + (w*8)*128;
        async_copy16(base,                 Abase + kt*64);
        async_copy16(base + 16384,         Bbase + kt*64);
        async_copy16(base + 16384 + 8192,  Bbase + (size_t)64*K + kt*64);
    };
    auto stage_p1 = [&](int kt, int b) {   // A rows 64-127, B rows 128-255
        char* base = sm + b*49152 + (w*8)*128;
        async_copy16(base + 8192,          Abase + (size_t)64*K  + kt*64);
        async_copy16(base + 16384 + 16384, Bbase + (size_t)128*K + kt*64);
        async_copy16(base + 16384 + 24576, Bbase + (size_t)192*K + kt*64);
    };

    const int nkt = K >> 6;    // 64

    // prologue: ktiles 0,1 into bufs 0,1; retire ktile0, keep ktile1 in flight
    stage_p0(0, 0); stage_p1(0, 0);
    stage_p0(1, 1); stage_p1(1, 1);
    VMC6();
    __builtin_amdgcn_s_barrier();

    int bc = 0;
    for (int t = 0; t < nkt; ++t) {
        const int b2 = (bc == 0) ? 2 : bc - 1;        // (bc+2)%3
        const bool st = (t + 2) < nkt;
        // phase 0: dk0 slice; stage half of ktile t+2
        O_RD(bc, 0);
        if (st) stage_p0(t + 2, b2);
        O_MFMA(); ENDBAR();
        // phase 1: dk1 slice; stage rest of ktile t+2; retire ktile t+1's stages
        O_RD(bc, 1);
        if (st) { stage_p1(t + 2, b2); O_MFMA(); VMC6(); }
        else    { O_MFMA(); VMC0(); }
        ENDBAR();
        bc = (bc == 2) ? 0 : bc + 1;
    }
    VMC0();  // drain before LDS dealloc

#pragma unroll
    for (int m = 0; m < 4; ++m)
#pragma unroll
        for (int n = 0; n < 4; ++n) {
            const int row = bm*128 + wm*64 + m*16 + g*4;
            const int col = bn*256 + wn*64 + n*16 + c0;
#pragma unroll
            for (int r = 0; r < 4; ++r)
                C[(size_t)(row + r) * N + col] = acc[m][n][r];
        }
}
#undef O_RD
#undef O_MFMA

// ---------------------------------------------------------------- flash attention
// (unchanged — validated rounds 2-6)
__global__ __launch_bounds__(256, 2) void attn_kernel(
    const u16* __restrict__ qkv, const u16* __restrict__ vT, u16* __restrict__ outp) {
    __shared__ __align__(16) char lds[65536];
    const int tid = threadIdx.x;
    const int w = tid >> 6, l = tid & 63;
    const int g = l >> 4, c0 = l & 15;
    const int qt = (blockIdx.y < 16) ? blockIdx.x : (15 - (int)blockIdx.x);
    const int h = blockIdx.y;
    const int kvh = h >> 2;
    const int q0g = qt * 128;
    const int qrow0 = q0g + w * 32;

    const int srK = w*4 + g,        scK = c0 ^ srK;
    const int srV = w*8 + (l >> 3), scV = (l & 7) ^ (l >> 3);

#pragma unroll
    for (int i = 0; i < 8; ++i)
        async_copy16(lds + (i*16 + w*4) * 256,
                     qkv + (size_t)(q0g + i*16 + srK) * 6144 + h*128 + scK*8);
    __syncthreads();

#pragma unroll
    for (int i = 0; i < 4; ++i)
        async_copy16(lds + 32768 + (i*16 + w*4) * 256,
                     qkv + (size_t)(i*16 + srK) * 6144 + 4096 + kvh*128 + scK*8);
#pragma unroll
    for (int i = 0; i < 4; ++i)
        async_copy16(lds + 49152 + (i*32 + w*8) * 128,
                     vT + (size_t)(kvh*128 + i*32 + srV) * 2048 + scV*8);

    bf16x8 qf[2][4];
#pragma unroll
    for (int i = 0; i < 2; ++i)
#pragma unroll
        for (int dks = 0; dks < 4; ++dks) {
            const int row = w*32 + i*16 + c0;
            qf[i][dks] = *(const bf16x8*)(lds + row*256 + (((dks*4 + g) ^ c0) * 16));
        }
    __syncthreads();

    f32x4 o[2][8] = {};
    float lsum[2] = {0.f, 0.f};
    const int ntiles = 2*qt + 2;
    const float SC2 = 0.08838834764831845f * 1.4426950408889634f;

    for (int kt = 0; kt < ntiles; ++kt) {
        const int cur = kt & 1;
        const char* kb = lds + (cur ? 0 : 32768);
        const char* vb = lds + (cur ? 16384 : 49152);
        if (kt + 1 < ntiles) {
            char* kbn = lds + ((cur ^ 1) ? 0 : 32768);
            char* vbn = lds + ((cur ^ 1) ? 16384 : 49152);
#pragma unroll
            for (int i = 0; i < 4; ++i)
                async_copy16(kbn + (i*16 + w*4) * 256,
                             qkv + (size_t)((kt+1)*64 + i*16 + srK) * 6144 + 4096 + kvh*128 + scK*8);
#pragma unroll
            for (int i = 0; i < 4; ++i)
                async_copy16(vbn + (i*32 + w*8) * 128,
                             vT + (size_t)(kvh*128 + i*32 + srV) * 2048 + (kt+1)*64 + scV*8);
        }

        if (kt*64 <= qrow0 + 31) {
            f32x4 st[2][4] = {};
            __builtin_amdgcn_s_setprio(1);
#pragma unroll
            for (int dks = 0; dks < 4; ++dks) {
                bf16x8 kf[4];
#pragma unroll
                for (int j = 0; j < 4; ++j) {
                    const int row = j*16 + c0;
                    kf[j] = *(const bf16x8*)(kb + row*256 + (((dks*4 + g) ^ c0) * 16));
                }
#pragma unroll
                for (int i = 0; i < 2; ++i)
#pragma unroll
                    for (int j = 0; j < 4; ++j)
                        st[i][j] = __builtin_amdgcn_mfma_f32_16x16x32_bf16(
                            kf[j], qf[i][dks], st[i][j], 0, 0, 0);
            }
            __builtin_amdgcn_s_setprio(0);

            const bool diag = (kt*64 + 63) > qrow0;
            u32 pk[2][4][2];
#pragma unroll
            for (int i = 0; i < 2; ++i) {
                float rowsum = 0.f;
#pragma unroll
                for (int j = 0; j < 4; ++j) {
#pragma unroll
                    for (int r = 0; r < 4; ++r) {
                        float p = exp2f(st[i][j][r] * SC2);
                        if (diag) {
                            const int kgl = kt*64 + j*16 + g*4 + r;
                            const int qgl = qrow0 + i*16 + c0;
                            if (kgl > qgl) p = 0.f;
                        }
                        st[i][j][r] = p;
                        rowsum += p;
                    }
                    pk[i][j][0] = cvt_pk_bf16(st[i][j][0], st[i][j][1]);
                    pk[i][j][1] = cvt_pk_bf16(st[i][j][2], st[i][j][3]);
                }
                rowsum += __shfl_xor(rowsum, 16);
                rowsum += __shfl_xor(rowsum, 32);
                lsum[i] += rowsum;
            }

#pragma unroll
            for (int dks = 0; dks < 2; ++dks) {
                bf16x8 pf[2];
#pragma unroll
                for (int i = 0; i < 2; ++i) {
                    union { u32 u[4]; bf16x8 v; } pu;
                    pu.u[0] = pk[i][2*dks][0];   pu.u[1] = pk[i][2*dks][1];
                    pu.u[2] = pk[i][2*dks+1][0]; pu.u[3] = pk[i][2*dks+1][1];
                    pf[i] = pu.v;
                }
                __builtin_amdgcn_s_setprio(1);
#pragma unroll
                for (int dj = 0; dj < 8; ++dj) {
                    const int row = dj*16 + c0;
                    const int cg0 = (4*dks + (g >> 1)) ^ (row & 7);
                    const int cg1 = (4*dks + (g >> 1) + 2) ^ (row & 7);
                    union { struct { bf16x4 lo, hi; } p; bf16x8 v; } vu;
                    vu.p.lo = *(const bf16x4*)(vb + row*128 + cg0*16 + 8*(g & 1));
                    vu.p.hi = *(const bf16x4*)(vb + row*128 + cg1*16 + 8*(g & 1));
#pragma unroll
                    for (int i = 0; i < 2; ++i)
                        o[i][dj] = __builtin_amdgcn_mfma_f32_16x16x32_bf16(
                            vu.v, pf[i], o[i][dj], 0, 0, 0);
                }
                __builtin_amdgcn_s_setprio(0);
            }
        }
        __syncthreads();
    }

#pragma unroll
    for (int i = 0; i < 2; ++i) {
        const float rcp = 1.0f / lsum[i];
        const int qg = qrow0 + i*16 + c0;
#pragma unroll
        for (int dj = 0; dj < 8; ++dj) {
            u16x4 ov = { f32_to_bf16bits(o[i][dj][0] * rcp),
                         f32_to_bf16bits(o[i][dj][1] * rcp),
                         f32_to_bf16bits(o[i][dj][2] * rcp),
                         f32_to_bf16bits(o[i][dj][3] * rcp) };
            *(u16x4*)(outp + (size_t)qg * 4096 + h*128 + dj*16 + g*4) = ov;
        }
    }
}

// ---------------------------------------------------------------- launcher
extern "C" void kernel_launch(void* const* d_in, const int* in_sizes, int n_in,
                              void* d_out, int out_size, void* d_ws, size_t ws_size,
                              hipStream_t stream) {
    const float* x    = (const float*)d_in[0];
    const float* wq   = (const float*)d_in[1];
    const float* wk   = (const float*)d_in[2];
    const float* wv   = (const float*)d_in[3];
    const float* wo   = (const float*)d_in[4];
    const float* cosp = (const float*)d_in[5];
    const float* sinp = (const float*)d_in[6];
    // d_in[7] = mask — causality applied analytically in attn_kernel.

    char* ws = (char*)d_ws;
    u16* xb    = (u16*)(ws);                       //  16.8 MB  x bf16 (2048x4096)
    u16* wqkvT = (u16*)(ws + 16777216);            //  50.3 MB  [wq|wk|wv]^T (6144x4096)
    u16* woT   = (u16*)(ws + 67108864);            //  33.6 MB  wo^T (4096x4096)
    u16* qkv   = (u16*)(ws + 100663296);           //  25.2 MB  qkv (2048x6144)
    u16* vTb   = (u16*)(ws + 125829120);           //   4.2 MB  v^T (1024x2048)
    u16* attn  = (u16*)(ws + 130023424);           //  16.8 MB  attn out (2048x4096)

    dim3 tb(32, 8);
    convert_f32_bf16<<<8192, 256, 0, stream>>>(x, xb, 2097152);
    transpose_wT<<<dim3(32, 128), tb, 0, stream>>>(wq, wqkvT, 4096, 4096);
    transpose_wT<<<dim3(8, 128),  tb, 0, stream>>>(wk, wqkvT + (size_t)4096*4096, 1024, 4096);
    transpose_wT<<<dim3(8, 128),  tb, 0, stream>>>(wv, wqkvT + (size_t)5120*4096, 1024, 4096);
    transpose_wT<<<dim3(32, 128), tb, 0, stream>>>(wo, woT, 4096, 4096);

    gemm_qkv<<<256, 512, 0, stream>>>(xb, wqkvT, qkv, 6144, 4096);
    rope_kernel<<<dim3(2048, 10), 256, 0, stream>>>((u32*)qkv, cosp, sinp);
    transpose_v<<<dim3(64, 32), tb, 0, stream>>>(qkv, vTb);
    attn_kernel<<<dim3(16, 32), 256, 0, stream>>>(qkv, vTb, attn);
    gemm_out<<<256, 512, 0, stream>>>(attn, woT, (float*)d_out, 4096, 4096);
}

// Round 9
// 314.355 us; speedup vs baseline: 1.0102x; 1.0005x over previous
//
#include <hip/hip_runtime.h>
#include <hip/hip_bf16.h>

typedef unsigned short u16;
typedef unsigned int   u32;
typedef __attribute__((ext_vector_type(8))) short bf16x8;
typedef __attribute__((ext_vector_type(4))) short bf16x4;
typedef __attribute__((ext_vector_type(4))) float f32x4;
typedef __attribute__((ext_vector_type(4))) unsigned short u16x4;

__device__ __forceinline__ u16 f32_to_bf16bits(float f) {
    u32 x = __float_as_uint(f);
    u32 r = (x + 0x7fffu + ((x >> 16) & 1u)) >> 16;   // RNE
    return (u16)r;
}
__device__ __forceinline__ float bf16bits_to_f32(u16 u) {
    return __uint_as_float(((u32)u) << 16);
}
__device__ __forceinline__ u32 cvt_pk_bf16(float lo, float hi) {
    u32 r;
    asm("v_cvt_pk_bf16_f32 %0, %1, %2" : "=v"(r) : "v"(lo), "v"(hi));
    return r;
}

// async global->LDS, 16B per lane. LDS dest is wave-uniform base + lane*16.
__device__ __forceinline__ void async_copy16(void* lds, const void* g) {
    __builtin_amdgcn_global_load_lds(
        (__attribute__((address_space(1))) void*)(g),
        (__attribute__((address_space(3))) void*)(lds), 16, 0, 0);
}

#define VMC6() asm volatile("s_waitcnt vmcnt(6)" ::: "memory")
#define VMC0() asm volatile("s_waitcnt vmcnt(0)" ::: "memory")
#define ENDBAR() __builtin_amdgcn_s_barrier()

// ---------------------------------------------------------------- convert x
__global__ void convert_f32_bf16(const float* __restrict__ src, u16* __restrict__ dst, int n4) {
    const int i = blockIdx.x * 256 + threadIdx.x;
    if (i >= n4) return;
    const float4 v = ((const float4*)src)[i];
    u16x4 o = { f32_to_bf16bits(v.x), f32_to_bf16bits(v.y),
                f32_to_bf16bits(v.z), f32_to_bf16bits(v.w) };
    ((u16x4*)dst)[i] = o;
}

// ------------------------------------------- weight transpose fp32(K,N)->bf16(N,K)
__global__ void transpose_wT(const float* __restrict__ src, u16* __restrict__ dst,
                             int N, int dstStride) {
    __shared__ float tile[32][129];
    const int n0 = blockIdx.x * 128, k0 = blockIdx.y * 32;
    const int tx = threadIdx.x, ty = threadIdx.y;      // (32, 8)
#pragma unroll
    for (int j = 0; j < 4; ++j)
#pragma unroll
        for (int i = 0; i < 4; ++i)
            tile[ty + 8*j][tx + 32*i] = src[(size_t)(k0 + ty + 8*j) * N + n0 + tx + 32*i];
    __syncthreads();
    const int tid = ty * 32 + tx;
    const int c = tid & 15, nl0 = tid >> 4;
#pragma unroll
    for (int s = 0; s < 8; ++s) {
        const int nl = nl0 + s * 16;
        const u32 pk = (u32)f32_to_bf16bits(tile[2*c][nl])
                     | ((u32)f32_to_bf16bits(tile[2*c + 1][nl]) << 16);
        *(u32*)&dst[(size_t)(n0 + nl) * dstStride + k0 + 2*c] = pk;
    }
}

// ------------------------------------------- V transpose bf16 (s,dcol)->(dcol,s)
__global__ void transpose_v(const u16* __restrict__ qkv, u16* __restrict__ vT) {
    __shared__ u16 tile[32][34];
    const int s0 = blockIdx.x * 32, n0 = blockIdx.y * 32;
    const int tx = threadIdx.x, ty = threadIdx.y;
#pragma unroll
    for (int i = 0; i < 4; ++i)
        tile[ty + i*8][tx] = qkv[(size_t)(s0 + ty + i*8) * 6144 + 5120 + n0 + tx];
    __syncthreads();
#pragma unroll
    for (int i = 0; i < 4; ++i)
        vT[(size_t)(n0 + ty + i*8) * 2048 + s0 + tx] = tile[tx][ty + i*8];
}

// ---------------------------------------------------------------- RoPE in place
__global__ void rope_kernel(u32* __restrict__ qkv, const float* __restrict__ cosp,
                            const float* __restrict__ sinp) {
    const int s = blockIdx.x;
    const int h = blockIdx.y * 4 + (threadIdx.x >> 6);
    const int p = threadIdx.x & 63;
    const size_t off = ((size_t)s * 6144 + h * 128) >> 1;
    const u32 packed = qkv[off + p];
    const float c  = cosp[s*64 + p], sn = sinp[s*64 + p];
    const float t1 = bf16bits_to_f32((u16)(packed & 0xffffu));
    const float t2 = bf16bits_to_f32((u16)(packed >> 16));
    const float o1 = t1 * c - t2 * sn;
    const float o2 = t1 * sn + t2 * c;
    qkv[off + p] = (u32)f32_to_bf16bits(o1) | ((u32)f32_to_bf16bits(o2) << 16);
}

// ---------------------------------------------------------------- qkv GEMM
// C[2048,6144] = A[2048,4096] * B[6144,4096]^T.  BM=128, BN=384, BK=64.
// Grid 256 (full chip).  8 waves (2m x 4n); wave = 64r x 96c (4m x 6n frags).
// Phases sliced by K-half (dk) to balance LDS reads: per ktile
//   p0: rd B[dk0](6)+A01[dk0](2) -> MFMA (m01,dk0)=12
//   p1: rd B[dk1](6)+A23[dk0](2) -> MFMA (m23,dk0)=12   (B reads done by p1)
//   p2: rd A01[dk1](2)           -> MFMA (m01,dk1)=12
//   p3: rd A23[dk1](2)           -> MFMA (m23,dk1)=12
// Staging skeleton identical to validated round-6 kernel (A at p0/p1/p4/p5,
// B at p2/p3/p6/p7, vmcnt(6) at p3/p7, vmcnt(0) on guarded tail).
#define Q_RD_BF(d, dk) do { _Pragma("unroll")                                  \
    for (int ni = 0; ni < 6; ++ni) {                                           \
        const char* bb = sm + 32768 + ((d)*2 + bh)*24576                       \
                       + ((wn&1)*96 + ni*16 + c0)*128;                         \
        bfr[ni][dk] = *(const bf16x8*)(bb + ((((dk)*4 + g) ^ (c0&7)) * 16));   \
    } } while (0)

#define Q_RD_AF(dst, d, mh, dk) do { _Pragma("unroll")                         \
    for (int mi = 0; mi < 2; ++mi) {                                           \
        const char* ab = sm + ((d)*2 + wm)*8192 + (((mh)*2+mi)*16 + c0)*128;   \
        dst[mi] = *(const bf16x8*)(ab + ((((dk)*4 + g) ^ (c0&7)) * 16));       \
    } } while (0)

#define Q_MFMA(MH, DK, AFR) do {                                               \
    __builtin_amdgcn_s_barrier();                                              \
    asm volatile("s_waitcnt lgkmcnt(0)" ::: "memory");                         \
    __builtin_amdgcn_sched_barrier(0);                                         \
    __builtin_amdgcn_s_setprio(1);                                             \
    _Pragma("unroll") for (int mi = 0; mi < 2; ++mi)                           \
    _Pragma("unroll") for (int ni = 0; ni < 6; ++ni)                           \
        acc[(MH)*2+mi][ni] = __builtin_amdgcn_mfma_f32_16x16x32_bf16(          \
            AFR[mi], bfr[ni][DK], acc[(MH)*2+mi][ni], 0,0,0);                  \
    __builtin_amdgcn_s_setprio(0); } while (0)

__global__ __launch_bounds__(512, 2) void gemm_qkv(
    const u16* __restrict__ A, const u16* __restrict__ B, u16* __restrict__ C,
    const int N, const int K) {
    __shared__ __align__(16) char sm[131072];
    const int tid = threadIdx.x;
    const int w = tid >> 6, l = tid & 63;
    const int wm = w >> 2, wn = w & 3, bh = wn >> 1;
    const int g = l >> 4, c0 = l & 15;
    const int bm = blockIdx.x >> 4, bn = blockIdx.x & 15;

    const int srow   = w*8 + (l >> 3);
    const int schunk = (l & 7) ^ (l >> 3);
    const u16* Abase = A + (size_t)(bm*128 + srow) * K + schunk*8;
    const u16* Bbase = B + (size_t)(bn*384 + srow) * K + schunk*8;

    f32x4 acc[4][6] = {};
    bf16x8 bfr[6][2], afa[2], afb[2];

    auto stageA = [&](int kt, int d, int h) {
        async_copy16(sm + (d*2 + h)*8192 + (w*8)*128,
                     Abase + (size_t)h*64*K + kt*64);
    };
    auto stageB = [&](int kt, int d, int h) {
        char* dst = sm + 32768 + (d*2 + h)*24576 + (w*8)*128;
        const u16* src = Bbase + (size_t)h*192*K + kt*64;
#pragma unroll
        for (int r = 0; r < 3; ++r)
            async_copy16(dst + r*8192, src + (size_t)r*64*K);
    };

    const int nkt = K >> 6;    // 64

    // prologue: ktile0 full + ktile1 B halves; retire ktile0, keep B1 in flight
    stageB(0, 0, 0); stageB(0, 0, 1);
    stageA(0, 0, 0); stageA(0, 0, 1);
    stageB(1, 1, 0); stageB(1, 1, 1);
    VMC6();
    __builtin_amdgcn_s_barrier();

    for (int t = 0; t < nkt; t += 2) {
        const int tb = t + 1, tc = t + 2, td = t + 3;
        // ---- ktile t (buf0) ----
        Q_RD_BF(0, 0); Q_RD_AF(afa, 0, 0, 0); stageA(tb, 1, 0);
        Q_MFMA(0, 0, afa); ENDBAR();
        Q_RD_BF(0, 1); Q_RD_AF(afb, 0, 1, 0); stageA(tb, 1, 1);
        Q_MFMA(1, 0, afb); ENDBAR();
        Q_RD_AF(afa, 0, 0, 1); if (tc < nkt) stageB(tc, 0, 0);
        Q_MFMA(0, 1, afa); ENDBAR();
        Q_RD_AF(afb, 0, 1, 1);
        if (tc < nkt) { stageB(tc, 0, 1); Q_MFMA(1, 1, afb); VMC6(); }
        else          { Q_MFMA(1, 1, afb); VMC0(); }
        ENDBAR();
        // ---- ktile t+1 (buf1) ----
        Q_RD_BF(1, 0); Q_RD_AF(afa, 1, 0, 0); if (tc < nkt) stageA(tc, 0, 0);
        Q_MFMA(0, 0, afa); ENDBAR();
        Q_RD_BF(1, 1); Q_RD_AF(afb, 1, 1, 0); if (tc < nkt) stageA(tc, 0, 1);
        Q_MFMA(1, 0, afb); ENDBAR();
        Q_RD_AF(afa, 1, 0, 1); if (td < nkt) stageB(td, 1, 0);
        Q_MFMA(0, 1, afa); ENDBAR();
        Q_RD_AF(afb, 1, 1, 1);
        if (td < nkt) { stageB(td, 1, 1); Q_MFMA(1, 1, afb); VMC6(); }
        else          { Q_MFMA(1, 1, afb); VMC0(); }
        ENDBAR();
    }
    VMC0();  // drain before LDS dealloc

#pragma unroll
    for (int m = 0; m < 4; ++m)
#pragma unroll
        for (int n = 0; n < 6; ++n) {
            const int row = bm*128 + wm*64 + m*16 + g*4;
            const int col = bn*384 + wn*96 + n*16 + c0;
#pragma unroll
            for (int r = 0; r < 4; ++r)
                C[(size_t)(row + r) * N + col] = f32_to_bf16bits(acc[m][n][r]);
        }
}
#undef Q_RD_BF
#undef Q_RD_AF
#undef Q_MFMA

// ---------------------------------------------------------------- out-proj GEMM
// C[2048,4096](f32) = A[2048,4096] * B[4096,4096]^T.  BM=128, BN=256, BK=64.
// Grid 256.  8 waves (2m x 4n); wave = 64r x 64c (4m x 4n frags).
// TRIPLE-buffered LDS (3 x 48KB); 2 phases/ktile sliced by dk:
//   each phase: rd A[dk](4) + B[dk](4) = 8 reads -> 16 MFMA.  Balanced 8/8.
// Stage ktile t+2 into buf (t+2)%3; vmcnt(6) once per ktile.
#define O_RD(b, dk) do { _Pragma("unroll")                                     \
    for (int mi = 0; mi < 4; ++mi) {                                           \
        const char* ab = sm + (b)*49152 + (wm*64 + mi*16 + c0)*128;            \
        af[mi] = *(const bf16x8*)(ab + ((((dk)*4+g) ^ (c0&7)) * 16));          \
    }                                                                          \
    _Pragma("unroll")                                                          \
    for (int nj = 0; nj < 4; ++nj) {                                           \
        const char* bb = sm + (b)*49152 + 16384 + (wn*64 + nj*16 + c0)*128;    \
        bfv[nj] = *(const bf16x8*)(bb + ((((dk)*4+g) ^ (c0&7)) * 16));         \
    } } while (0)

#define O_MFMA() do {                                                          \
    __builtin_amdgcn_s_barrier();                                              \
    asm volatile("s_waitcnt lgkmcnt(0)" ::: "memory");                         \
    __builtin_amdgcn_sched_barrier(0);                                         \
    __builtin_amdgcn_s_setprio(1);                                             \
    _Pragma("unroll") for (int mi = 0; mi < 4; ++mi)                           \
    _Pragma("unroll") for (int nj = 0; nj < 4; ++nj)                           \
        acc[mi][nj] = __builtin_amdgcn_mfma_f32_16x16x32_bf16(                 \
            af[mi], bfv[nj], acc[mi][nj], 0,0,0);                              \
    __builtin_amdgcn_s_setprio(0); } while (0)

__global__ __launch_bounds__(512, 2) void gemm_out(
    const u16* __restrict__ A, const u16* __restrict__ B, float* __restrict__ C,
    const int N, const int K) {
    __shared__ __align__(16) char sm[147456];
    const int tid = threadIdx.x;
    const int w = tid >> 6, l = tid & 63;
    const int wm = w >> 2, wn = w & 3;
    const int g = l >> 4, c0 = l & 15;
    const int bm = blockIdx.x >> 4, bn = blockIdx.x & 15;

    const int srow   = w*8 + (l >> 3);
    const int schunk = (l & 7) ^ (l >> 3);
    const u16* Abase = A + (size_t)(bm*128 + srow) * K + schunk*8;
    const u16* Bbase = B + (size_t)(bn*256 + srow) * K + schunk*8;

    f32x4 acc[4][4] = {};
    bf16x8 af[4], bfv[4];

    auto stage_p0 = [&](int kt, int b) {   // A rows 0-63, B rows 0-127
        char* base = sm + b*49152 + (w*8)*128;
        async_copy16(base,                 Abase + kt*64);
        async_copy16(base + 16384,         Bbase + kt*64);
        async_copy16(base + 16384 + 8192,  Bbase + (size_t)64*K + kt*64);
    };
    auto stage_p1 = [&](int kt, int b) {   // A rows 64-127, B rows 128-255
        char* base = sm + b*49152 + (w*8)*128;
        async_copy16(base + 8192,          Abase + (size_t)64*K  + kt*64);
        async_copy16(base + 16384 + 16384, Bbase + (size_t)128*K + kt*64);
        async_copy16(base + 16384 + 24576, Bbase + (size_t)192*K + kt*64);
    };

    const int nkt = K >> 6;    // 64

    // prologue: ktiles 0,1 into bufs 0,1; retire ktile0, keep ktile1 in flight
    stage_p0(0, 0); stage_p1(0, 0);
    stage_p0(1, 1); stage_p1(1, 1);
    VMC6();
    __builtin_amdgcn_s_barrier();

    int bc = 0;
    for (int t = 0; t < nkt; ++t) {
        const int b2 = (bc == 0) ? 2 : bc - 1;        // (bc+2)%3
        const bool st = (t + 2) < nkt;
        // phase 0: dk0 slice; stage half of ktile t+2
        O_RD(bc, 0);
        if (st) stage_p0(t + 2, b2);
        O_MFMA(); ENDBAR();
        // phase 1: dk1 slice; stage rest of ktile t+2; retire ktile t+1's stages
        O_RD(bc, 1);
        if (st) { stage_p1(t + 2, b2); O_MFMA(); VMC6(); }
        else    { O_MFMA(); VMC0(); }
        ENDBAR();
        bc = (bc == 2) ? 0 : bc + 1;
    }
    VMC0();  // drain before LDS dealloc

#pragma unroll
    for (int m = 0; m < 4; ++m)
#pragma unroll
        for (int n = 0; n < 4; ++n) {
            const int row = bm*128 + wm*64 + m*16 + g*4;
            const int col = bn*256 + wn*64 + n*16 + c0;
#pragma unroll
            for (int r = 0; r < 4; ++r)
                C[(size_t)(row + r) * N + col] = acc[m][n][r];
        }
}
#undef O_RD
#undef O_MFMA

// ---------------------------------------------------------------- flash attention
// (unchanged — validated rounds 2-6)
__global__ __launch_bounds__(256, 2) void attn_kernel(
    const u16* __restrict__ qkv, const u16* __restrict__ vT, u16* __restrict__ outp) {
    __shared__ __align__(16) char lds[65536];
    const int tid = threadIdx.x;
    const int w = tid >> 6, l = tid & 63;
    const int g = l >> 4, c0 = l & 15;
    const int qt = (blockIdx.y < 16) ? blockIdx.x : (15 - (int)blockIdx.x);
    const int h = blockIdx.y;
    const int kvh = h >> 2;
    const int q0g = qt * 128;
    const int qrow0 = q0g + w * 32;

    const int srK = w*4 + g,        scK = c0 ^ srK;
    const int srV = w*8 + (l >> 3), scV = (l & 7) ^ (l >> 3);

#pragma unroll
    for (int i = 0; i < 8; ++i)
        async_copy16(lds + (i*16 + w*4) * 256,
                     qkv + (size_t)(q0g + i*16 + srK) * 6144 + h*128 + scK*8);
    __syncthreads();

#pragma unroll
    for (int i = 0; i < 4; ++i)
        async_copy16(lds + 32768 + (i*16 + w*4) * 256,
                     qkv + (size_t)(i*16 + srK) * 6144 + 4096 + kvh*128 + scK*8);
#pragma unroll
    for (int i = 0; i < 4; ++i)
        async_copy16(lds + 49152 + (i*32 + w*8) * 128,
                     vT + (size_t)(kvh*128 + i*32 + srV) * 2048 + scV*8);

    bf16x8 qf[2][4];
#pragma unroll
    for (int i = 0; i < 2; ++i)
#pragma unroll
        for (int dks = 0; dks < 4; ++dks) {
            const int row = w*32 + i*16 + c0;
            qf[i][dks] = *(const bf16x8*)(lds + row*256 + (((dks*4 + g) ^ c0) * 16));
        }
    __syncthreads();

    f32x4 o[2][8] = {};
    float lsum[2] = {0.f, 0.f};
    const int ntiles = 2*qt + 2;
    const float SC2 = 0.08838834764831845f * 1.4426950408889634f;

    for (int kt = 0; kt < ntiles; ++kt) {
        const int cur = kt & 1;
        const char* kb = lds + (cur ? 0 : 32768);
        const char* vb = lds + (cur ? 16384 : 49152);
        if (kt + 1 < ntiles) {
            char* kbn = lds + ((cur ^ 1) ? 0 : 32768);
            char* vbn = lds + ((cur ^ 1) ? 16384 : 49152);
#pragma unroll
            for (int i = 0; i < 4; ++i)
                async_copy16(kbn + (i*16 + w*4) * 256,
                             qkv + (size_t)((kt+1)*64 + i*16 + srK) * 6144 + 4096 + kvh*128 + scK*8);
#pragma unroll
            for (int i = 0; i < 4; ++i)
                async_copy16(vbn + (i*32 + w*8) * 128,
                             vT + (size_t)(kvh*128 + i*32 + srV) * 2048 + (kt+1)*64 + scV*8);
        }

        if (kt*64 <= qrow0 + 31) {
            f32x4 st[2][4] = {};
            __builtin_amdgcn_s_setprio(1);
#pragma unroll
            for (int dks = 0; dks < 4; ++dks) {
                bf16x8 kf[4];
#pragma unroll
                for (int j = 0; j < 4; ++j) {
                    const int row = j*16 + c0;
                    kf[j] = *(const bf16x8*)(kb + row*256 + (((dks*4 + g) ^ c0) * 16));
                }
#pragma unroll
                for (int i = 0; i < 2; ++i)
#pragma unroll
                    for (int j = 0; j < 4; ++j)
                        st[i][j] = __builtin_amdgcn_mfma_f32_16x16x32_bf16(
                            kf[j], qf[i][dks], st[i][j], 0, 0, 0);
            }
            __builtin_amdgcn_s_setprio(0);

            const bool diag = (kt*64 + 63) > qrow0;
            u32 pk[2][4][2];
#pragma unroll
            for (int i = 0; i < 2; ++i) {
                float rowsum = 0.f;
#pragma unroll
                for (int j = 0; j < 4; ++j) {
#pragma unroll
                    for (int r = 0; r < 4; ++r) {
                        float p = exp2f(st[i][j][r] * SC2);
                        if (diag) {
                            const int kgl = kt*64 + j*16 + g*4 + r;
                            const int qgl = qrow0 + i*16 + c0;
                            if (kgl > qgl) p = 0.f;
                        }
                        st[i][j][r] = p;
                        rowsum += p;
                    }
                    pk[i][j][0] = cvt_pk_bf16(st[i][j][0], st[i][j][1]);
                    pk[i][j][1] = cvt_pk_bf16(st[i][j][2], st[i][j][3]);
                }
                rowsum += __shfl_xor(rowsum, 16);
                rowsum += __shfl_xor(rowsum, 32);
                lsum[i] += rowsum;
            }

#pragma unroll
            for (int dks = 0; dks < 2; ++dks) {
                bf16x8 pf[2];
#pragma unroll
                for (int i = 0; i < 2; ++i) {
                    union { u32 u[4]; bf16x8 v; } pu;
                    pu.u[0] = pk[i][2*dks][0];   pu.u[1] = pk[i][2*dks][1];
                    pu.u[2] = pk[i][2*dks+1][0]; pu.u[3] = pk[i][2*dks+1][1];
                    pf[i] = pu.v;
                }
                __builtin_amdgcn_s_setprio(1);
#pragma unroll
                for (int dj = 0; dj < 8; ++dj) {
                    const int row = dj*16 + c0;
                    const int cg0 = (4*dks + (g >> 1)) ^ (row & 7);
                    const int cg1 = (4*dks + (g >> 1) + 2) ^ (row & 7);
                    union { struct { bf16x4 lo, hi; } p; bf16x8 v; } vu;
                    vu.p.lo = *(const bf16x4*)(vb + row*128 + cg0*16 + 8*(g & 1));
                    vu.p.hi = *(const bf16x4*)(vb + row*128 + cg1*16 + 8*(g & 1));
#pragma unroll
                    for (int i = 0; i < 2; ++i)
                        o[i][dj] = __builtin_amdgcn_mfma_f32_16x16x32_bf16(
                            vu.v, pf[i], o[i][dj], 0, 0, 0);
                }
                __builtin_amdgcn_s_setprio(0);
            }
        }
        __syncthreads();
    }

#pragma unroll
    for (int i = 0; i < 2; ++i) {
        const float rcp = 1.0f / lsum[i];
        const int qg = qrow0 + i*16 + c0;
#pragma unroll
        for (int dj = 0; dj < 8; ++dj) {
            u16x4 ov = { f32_to_bf16bits(o[i][dj][0] * rcp),
                         f32_to_bf16bits(o[i][dj][1] * rcp),
                         f32_to_bf16bits(o[i][dj][2] * rcp),
                         f32_to_bf16bits(o[i][dj][3] * rcp) };
            *(u16x4*)(outp + (size_t)qg * 4096 + h*128 + dj*16 + g*4) = ov;
        }
    }
}

// ---------------------------------------------------------------- launcher
extern "C" void kernel_launch(void* const* d_in, const int* in_sizes, int n_in,
                              void* d_out, int out_size, void* d_ws, size_t ws_size,
                              hipStream_t stream) {
    const float* x    = (const float*)d_in[0];
    const float* wq   = (const float*)d_in[1];
    const float* wk   = (const float*)d_in[2];
    const float* wv   = (const float*)d_in[3];
    const float* wo   = (const float*)d_in[4];
    const float* cosp = (const float*)d_in[5];
    const float* sinp = (const float*)d_in[6];
    // d_in[7] = mask — causality applied analytically in attn_kernel.

    char* ws = (char*)d_ws;
    u16* xb    = (u16*)(ws);                       //  16.8 MB  x bf16 (2048x4096)
    u16* wqkvT = (u16*)(ws + 16777216);            //  50.3 MB  [wq|wk|wv]^T (6144x4096)
    u16* woT   = (u16*)(ws + 67108864);            //  33.6 MB  wo^T (4096x4096)
    u16* qkv   = (u16*)(ws + 100663296);           //  25.2 MB  qkv (2048x6144)
    u16* vTb   = (u16*)(ws + 125829120);           //   4.2 MB  v^T (1024x2048)
    u16* attn  = (u16*)(ws + 130023424);           //  16.8 MB  attn out (2048x4096)

    dim3 tb(32, 8);
    convert_f32_bf16<<<8192, 256, 0, stream>>>(x, xb, 2097152);
    transpose_wT<<<dim3(32, 128), tb, 0, stream>>>(wq, wqkvT, 4096, 4096);
    transpose_wT<<<dim3(8, 128),  tb, 0, stream>>>(wk, wqkvT + (size_t)4096*4096, 1024, 4096);
    transpose_wT<<<dim3(8, 128),  tb, 0, stream>>>(wv, wqkvT + (size_t)5120*4096, 1024, 4096);
    transpose_wT<<<dim3(32, 128), tb, 0, stream>>>(wo, woT, 4096, 4096);

    gemm_qkv<<<256, 512, 0, stream>>>(xb, wqkvT, qkv, 6144, 4096);
    rope_kernel<<<dim3(2048, 10), 256, 0, stream>>>((u32*)qkv, cosp, sinp);
    transpose_v<<<dim3(64, 32), tb, 0, stream>>>(qkv, vTb);
    attn_kernel<<<dim3(16, 32), 256, 0, stream>>>(qkv, vTb, attn);
    gemm_out<<<256, 512, 0, stream>>>(attn, woT, (float*)d_out, 4096, 4096);
}

// Round 10
// 314.286 us; speedup vs baseline: 1.0104x; 1.0002x over previous
//
#include <hip/hip_runtime.h>
#include <hip/hip_bf16.h>

typedef unsigned short u16;
typedef unsigned int   u32;
typedef __attribute__((ext_vector_type(8))) short bf16x8;
typedef __attribute__((ext_vector_type(4))) short bf16x4;
typedef __attribute__((ext_vector_type(4))) float f32x4;
typedef __attribute__((ext_vector_type(4))) unsigned short u16x4;

__device__ __forceinline__ u16 f32_to_bf16bits(float f) {
    u32 x = __float_as_uint(f);
    u32 r = (x + 0x7fffu + ((x >> 16) & 1u)) >> 16;   // RNE
    return (u16)r;
}
__device__ __forceinline__ float bf16bits_to_f32(u16 u) {
    return __uint_as_float(((u32)u) << 16);
}
__device__ __forceinline__ u32 cvt_pk_bf16(float lo, float hi) {
    u32 r;
    asm("v_cvt_pk_bf16_f32 %0, %1, %2" : "=v"(r) : "v"(lo), "v"(hi));
    return r;
}

// async global->LDS, 16B per lane. LDS dest is wave-uniform base + lane*16.
__device__ __forceinline__ void async_copy16(void* lds, const void* g) {
    __builtin_amdgcn_global_load_lds(
        (__attribute__((address_space(1))) void*)(g),
        (__attribute__((address_space(3))) void*)(lds), 16, 0, 0);
}

#define VMC6() asm volatile("s_waitcnt vmcnt(6)" ::: "memory")
#define VMC0() asm volatile("s_waitcnt vmcnt(0)" ::: "memory")
#define ENDBAR() __builtin_amdgcn_s_barrier()

// ---------------------------------------------------------------- convert x
__global__ void convert_f32_bf16(const float* __restrict__ src, u16* __restrict__ dst, int n4) {
    const int i = blockIdx.x * 256 + threadIdx.x;
    if (i >= n4) return;
    const float4 v = ((const float4*)src)[i];
    u16x4 o = { f32_to_bf16bits(v.x), f32_to_bf16bits(v.y),
                f32_to_bf16bits(v.z), f32_to_bf16bits(v.w) };
    ((u16x4*)dst)[i] = o;
}

// ------------------------------------------- weight transpose fp32(K,N)->bf16(N,K)
__global__ void transpose_wT(const float* __restrict__ src, u16* __restrict__ dst,
                             int N, int dstStride) {
    __shared__ float tile[32][129];
    const int n0 = blockIdx.x * 128, k0 = blockIdx.y * 32;
    const int tx = threadIdx.x, ty = threadIdx.y;      // (32, 8)
#pragma unroll
    for (int j = 0; j < 4; ++j)
#pragma unroll
        for (int i = 0; i < 4; ++i)
            tile[ty + 8*j][tx + 32*i] = src[(size_t)(k0 + ty + 8*j) * N + n0 + tx + 32*i];
    __syncthreads();
    const int tid = ty * 32 + tx;
    const int c = tid & 15, nl0 = tid >> 4;
#pragma unroll
    for (int s = 0; s < 8; ++s) {
        const int nl = nl0 + s * 16;
        const u32 pk = (u32)f32_to_bf16bits(tile[2*c][nl])
                     | ((u32)f32_to_bf16bits(tile[2*c + 1][nl]) << 16);
        *(u32*)&dst[(size_t)(n0 + nl) * dstStride + k0 + 2*c] = pk;
    }
}

// ------------------------------------------- V transpose bf16 (s,dcol)->(dcol,s)
__global__ void transpose_v(const u16* __restrict__ qkv, u16* __restrict__ vT) {
    __shared__ u16 tile[32][34];
    const int s0 = blockIdx.x * 32, n0 = blockIdx.y * 32;
    const int tx = threadIdx.x, ty = threadIdx.y;
#pragma unroll
    for (int i = 0; i < 4; ++i)
        tile[ty + i*8][tx] = qkv[(size_t)(s0 + ty + i*8) * 6144 + 5120 + n0 + tx];
    __syncthreads();
#pragma unroll
    for (int i = 0; i < 4; ++i)
        vT[(size_t)(n0 + ty + i*8) * 2048 + s0 + tx] = tile[tx][ty + i*8];
}

// ---------------------------------------------------------------- RoPE in place
__global__ void rope_kernel(u32* __restrict__ qkv, const float* __restrict__ cosp,
                            const float* __restrict__ sinp) {
    const int s = blockIdx.x;
    const int h = blockIdx.y * 4 + (threadIdx.x >> 6);
    const int p = threadIdx.x & 63;
    const size_t off = ((size_t)s * 6144 + h * 128) >> 1;
    const u32 packed = qkv[off + p];
    const float c  = cosp[s*64 + p], sn = sinp[s*64 + p];
    const float t1 = bf16bits_to_f32((u16)(packed & 0xffffu));
    const float t2 = bf16bits_to_f32((u16)(packed >> 16));
    const float o1 = t1 * c - t2 * sn;
    const float o2 = t1 * sn + t2 * c;
    qkv[off + p] = (u32)f32_to_bf16bits(o1) | ((u32)f32_to_bf16bits(o2) << 16);
}

// ---------------------------------------------------------------- qkv GEMM
// C[2048,6144] = A[2048,4096] * B[6144,4096]^T.  BM=128, BN=384, BK=64.
// Grid 256 (full chip).  8 waves (2m x 4n); wave = 64r x 96c (4m x 6n frags).
// Phases sliced by K-half (dk) to balance LDS reads: per ktile
//   p0: rd B[dk0](6)+A01[dk0](2) -> MFMA (m01,dk0)=12
//   p1: rd B[dk1](6)+A23[dk0](2) -> MFMA (m23,dk0)=12   (B reads done by p1)
//   p2: rd A01[dk1](2)           -> MFMA (m01,dk1)=12
//   p3: rd A23[dk1](2)           -> MFMA (m23,dk1)=12
// Staging skeleton identical to validated round-6 kernel (A at p0/p1/p4/p5,
// B at p2/p3/p6/p7, vmcnt(6) at p3/p7, vmcnt(0) on guarded tail).
#define Q_RD_BF(d, dk) do { _Pragma("unroll")                                  \
    for (int ni = 0; ni < 6; ++ni) {                                           \
        const char* bb = sm + 32768 + ((d)*2 + bh)*24576                       \
                       + ((wn&1)*96 + ni*16 + c0)*128;                         \
        bfr[ni][dk] = *(const bf16x8*)(bb + ((((dk)*4 + g) ^ (c0&7)) * 16));   \
    } } while (0)

#define Q_RD_AF(dst, d, mh, dk) do { _Pragma("unroll")                         \
    for (int mi = 0; mi < 2; ++mi) {                                           \
        const char* ab = sm + ((d)*2 + wm)*8192 + (((mh)*2+mi)*16 + c0)*128;   \
        dst[mi] = *(const bf16x8*)(ab + ((((dk)*4 + g) ^ (c0&7)) * 16));       \
    } } while (0)

#define Q_MFMA(MH, DK, AFR) do {                                               \
    __builtin_amdgcn_s_barrier();                                              \
    asm volatile("s_waitcnt lgkmcnt(0)" ::: "memory");                         \
    __builtin_amdgcn_sched_barrier(0);                                         \
    __builtin_amdgcn_s_setprio(1);                                             \
    _Pragma("unroll") for (int mi = 0; mi < 2; ++mi)                           \
    _Pragma("unroll") for (int ni = 0; ni < 6; ++ni)                           \
        acc[(MH)*2+mi][ni] = __builtin_amdgcn_mfma_f32_16x16x32_bf16(          \
            AFR[mi], bfr[ni][DK], acc[(MH)*2+mi][ni], 0,0,0);                  \
    __builtin_amdgcn_s_setprio(0); } while (0)

__global__ __launch_bounds__(512, 2) void gemm_qkv(
    const u16* __restrict__ A, const u16* __restrict__ B, u16* __restrict__ C,
    const int N, const int K) {
    __shared__ __align__(16) char sm[131072];
    const int tid = threadIdx.x;
    const int w = tid >> 6, l = tid & 63;
    const int wm = w >> 2, wn = w & 3, bh = wn >> 1;
    const int g = l >> 4, c0 = l & 15;
    const int bm = blockIdx.x >> 4, bn = blockIdx.x & 15;

    const int srow   = w*8 + (l >> 3);
    const int schunk = (l & 7) ^ (l >> 3);
    const u16* Abase = A + (size_t)(bm*128 + srow) * K + schunk*8;
    const u16* Bbase = B + (size_t)(bn*384 + srow) * K + schunk*8;

    f32x4 acc[4][6] = {};
    bf16x8 bfr[6][2], afa[2], afb[2];

    auto stageA = [&](int kt, int d, int h) {
        async_copy16(sm + (d*2 + h)*8192 + (w*8)*128,
                     Abase + (size_t)h*64*K + kt*64);
    };
    auto stageB = [&](int kt, int d, int h) {
        char* dst = sm + 32768 + (d*2 + h)*24576 + (w*8)*128;
        const u16* src = Bbase + (size_t)h*192*K + kt*64;
#pragma unroll
        for (int r = 0; r < 3; ++r)
            async_copy16(dst + r*8192, src + (size_t)r*64*K);
    };

    const int nkt = K >> 6;    // 64

    // prologue: ktile0 full + ktile1 B halves; retire ktile0, keep B1 in flight
    stageB(0, 0, 0); stageB(0, 0, 1);
    stageA(0, 0, 0); stageA(0, 0, 1);
    stageB(1, 1, 0); stageB(1, 1, 1);
    VMC6();
    __builtin_amdgcn_s_barrier();

    for (int t = 0; t < nkt; t += 2) {
        const int tb = t + 1, tc = t + 2, td = t + 3;
        // ---- ktile t (buf0) ----
        Q_RD_BF(0, 0); Q_RD_AF(afa, 0, 0, 0); stageA(tb, 1, 0);
        Q_MFMA(0, 0, afa); ENDBAR();
        Q_RD_BF(0, 1); Q_RD_AF(afb, 0, 1, 0); stageA(tb, 1, 1);
        Q_MFMA(1, 0, afb); ENDBAR();
        Q_RD_AF(afa, 0, 0, 1); if (tc < nkt) stageB(tc, 0, 0);
        Q_MFMA(0, 1, afa); ENDBAR();
        Q_RD_AF(afb, 0, 1, 1);
        if (tc < nkt) { stageB(tc, 0, 1); Q_MFMA(1, 1, afb); VMC6(); }
        else          { Q_MFMA(1, 1, afb); VMC0(); }
        ENDBAR();
        // ---- ktile t+1 (buf1) ----
        Q_RD_BF(1, 0); Q_RD_AF(afa, 1, 0, 0); if (tc < nkt) stageA(tc, 0, 0);
        Q_MFMA(0, 0, afa); ENDBAR();
        Q_RD_BF(1, 1); Q_RD_AF(afb, 1, 1, 0); if (tc < nkt) stageA(tc, 0, 1);
        Q_MFMA(1, 0, afb); ENDBAR();
        Q_RD_AF(afa, 1, 0, 1); if (td < nkt) stageB(td, 1, 0);
        Q_MFMA(0, 1, afa); ENDBAR();
        Q_RD_AF(afb, 1, 1, 1);
        if (td < nkt) { stageB(td, 1, 1); Q_MFMA(1, 1, afb); VMC6(); }
        else          { Q_MFMA(1, 1, afb); VMC0(); }
        ENDBAR();
    }
    VMC0();  // drain before LDS dealloc

#pragma unroll
    for (int m = 0; m < 4; ++m)
#pragma unroll
        for (int n = 0; n < 6; ++n) {
            const int row = bm*128 + wm*64 + m*16 + g*4;
            const int col = bn*384 + wn*96 + n*16 + c0;
#pragma unroll
            for (int r = 0; r < 4; ++r)
                C[(size_t)(row + r) * N + col] = f32_to_bf16bits(acc[m][n][r]);
        }
}
#undef Q_RD_BF
#undef Q_RD_AF
#undef Q_MFMA

// ---------------------------------------------------------------- out-proj GEMM
// C[2048,4096](f32) = A[2048,4096] * B[4096,4096]^T.  BM=128, BN=256, BK=64.
// Grid 256.  8 waves (2m x 4n); wave = 64r x 64c (4m x 4n frags).
// TRIPLE-buffered LDS (3 x 48KB); 2 phases/ktile sliced by dk:
//   each phase: rd A[dk](4) + B[dk](4) = 8 reads -> 16 MFMA.  Balanced 8/8.
// Stage ktile t+2 into buf (t+2)%3; vmcnt(6) once per ktile.
#define O_RD(b, dk) do { _Pragma("unroll")                                     \
    for (int mi = 0; mi < 4; ++mi) {                                           \
        const char* ab = sm + (b)*49152 + (wm*64 + mi*16 + c0)*128;            \
        af[mi] = *(const bf16x8*)(ab + ((((dk)*4+g) ^ (c0&7)) * 16));          \
    }                                                                          \
    _Pragma("unroll")                                                          \
    for (int nj = 0; nj < 4; ++nj) {                                           \
        const char* bb = sm + (b)*49152 + 16384 + (wn*64 + nj*16 + c0)*128;    \
        bfv[nj] = *(const bf16x8*)(bb + ((((dk)*4+g) ^ (c0&7)) * 16));         \
    } } while (0)

#define O_MFMA() do {                                                          \
    __builtin_amdgcn_s_barrier();                                              \
    asm volatile("s_waitcnt lgkmcnt(0)" ::: "memory");                         \
    __builtin_amdgcn_sched_barrier(0);                                         \
    __builtin_amdgcn_s_setprio(1);                                             \
    _Pragma("unroll") for (int mi = 0; mi < 4; ++mi)                           \
    _Pragma("unroll") for (int nj = 0; nj < 4; ++nj)                           \
        acc[mi][nj] = __builtin_amdgcn_mfma_f32_16x16x32_bf16(                 \
            af[mi], bfv[nj], acc[mi][nj], 0,0,0);                              \
    __builtin_amdgcn_s_setprio(0); } while (0)

__global__ __launch_bounds__(512, 2) void gemm_out(
    const u16* __restrict__ A, const u16* __restrict__ B, float* __restrict__ C,
    const int N, const int K) {
    __shared__ __align__(16) char sm[147456];
    const int tid = threadIdx.x;
    const int w = tid >> 6, l = tid & 63;
    const int wm = w >> 2, wn = w & 3;
    const int g = l >> 4, c0 = l & 15;
    const int bm = blockIdx.x >> 4, bn = blockIdx.x & 15;

    const int srow   = w*8 + (l >> 3);
    const int schunk = (l & 7) ^ (l >> 3);
    const u16* Abase = A + (size_t)(bm*128 + srow) * K + schunk*8;
    const u16* Bbase = B + (size_t)(bn*256 + srow) * K + schunk*8;

    f32x4 acc[4][4] = {};
    bf16x8 af[4], bfv[4];

    auto stage_p0 = [&](int kt, int b) {   // A rows 0-63, B rows 0-127
        char* base = sm + b*49152 + (w*8)*128;
        async_copy16(base,                 Abase + kt*64);
        async_copy16(base + 16384,         Bbase + kt*64);
        async_copy16(base + 16384 + 8192,  Bbase + (size_t)64*K + kt*64);
    };
    auto stage_p1 = [&](int kt, int b) {   // A rows 64-127, B rows 128-255
        char* base = sm + b*49152 + (w*8)*128;
        async_copy16(base + 8192,          Abase + (size_t)64*K  + kt*64);
        async_copy16(base + 16384 + 16384, Bbase + (size_t)128*K + kt*64);
        async_copy16(base + 16384 + 24576, Bbase + (size_t)192*K + kt*64);
    };

    const int nkt = K >> 6;    // 64

    // prologue: ktiles 0,1 into bufs 0,1; retire ktile0, keep ktile1 in flight
    stage_p0(0, 0); stage_p1(0, 0);
    stage_p0(1, 1); stage_p1(1, 1);
    VMC6();
    __builtin_amdgcn_s_barrier();

    int bc = 0;
    for (int t = 0; t < nkt; ++t) {
        const int b2 = (bc == 0) ? 2 : bc - 1;        // (bc+2)%3
        const bool st = (t + 2) < nkt;
        // phase 0: dk0 slice; stage half of ktile t+2
        O_RD(bc, 0);
        if (st) stage_p0(t + 2, b2);
        O_MFMA(); ENDBAR();
        // phase 1: dk1 slice; stage rest of ktile t+2; retire ktile t+1's stages
        O_RD(bc, 1);
        if (st) { stage_p1(t + 2, b2); O_MFMA(); VMC6(); }
        else    { O_MFMA(); VMC0(); }
        ENDBAR();
        bc = (bc == 2) ? 0 : bc + 1;
    }
    VMC0();  // drain before LDS dealloc

#pragma unroll
    for (int m = 0; m < 4; ++m)
#pragma unroll
        for (int n = 0; n < 4; ++n) {
            const int row = bm*128 + wm*64 + m*16 + g*4;
            const int col = bn*256 + wn*64 + n*16 + c0;
#pragma unroll
            for (int r = 0; r < 4; ++r)
                C[(size_t)(row + r) * N + col] = acc[m][n][r];
        }
}
#undef O_RD
#undef O_MFMA

// ---------------------------------------------------------------- flash attention
// (unchanged — validated rounds 2-6)
__global__ __launch_bounds__(256, 2) void attn_kernel(
    const u16* __restrict__ qkv, const u16* __restrict__ vT, u16* __restrict__ outp) {
    __shared__ __align__(16) char lds[65536];
    const int tid = threadIdx.x;
    const int w = tid >> 6, l = tid & 63;
    const int g = l >> 4, c0 = l & 15;
    const int qt = (blockIdx.y < 16) ? blockIdx.x : (15 - (int)blockIdx.x);
    const int h = blockIdx.y;
    const int kvh = h >> 2;
    const int q0g = qt * 128;
    const int qrow0 = q0g + w * 32;

    const int srK = w*4 + g,        scK = c0 ^ srK;
    const int srV = w*8 + (l >> 3), scV = (l & 7) ^ (l >> 3);

#pragma unroll
    for (int i = 0; i < 8; ++i)
        async_copy16(lds + (i*16 + w*4) * 256,
                     qkv + (size_t)(q0g + i*16 + srK) * 6144 + h*128 + scK*8);
    __syncthreads();

#pragma unroll
    for (int i = 0; i < 4; ++i)
        async_copy16(lds + 32768 + (i*16 + w*4) * 256,
                     qkv + (size_t)(i*16 + srK) * 6144 + 4096 + kvh*128 + scK*8);
#pragma unroll
    for (int i = 0; i < 4; ++i)
        async_copy16(lds + 49152 + (i*32 + w*8) * 128,
                     vT + (size_t)(kvh*128 + i*32 + srV) * 2048 + scV*8);

    bf16x8 qf[2][4];
#pragma unroll
    for (int i = 0; i < 2; ++i)
#pragma unroll
        for (int dks = 0; dks < 4; ++dks) {
            const int row = w*32 + i*16 + c0;
            qf[i][dks] = *(const bf16x8*)(lds + row*256 + (((dks*4 + g) ^ c0) * 16));
        }
    __syncthreads();

    f32x4 o[2][8] = {};
    float lsum[2] = {0.f, 0.f};
    const int ntiles = 2*qt + 2;
    const float SC2 = 0.08838834764831845f * 1.4426950408889634f;

    for (int kt = 0; kt < ntiles; ++kt) {
        const int cur = kt & 1;
        const char* kb = lds + (cur ? 0 : 32768);
        const char* vb = lds + (cur ? 16384 : 49152);
        if (kt + 1 < ntiles) {
            char* kbn = lds + ((cur ^ 1) ? 0 : 32768);
            char* vbn = lds + ((cur ^ 1) ? 16384 : 49152);
#pragma unroll
            for (int i = 0; i < 4; ++i)
                async_copy16(kbn + (i*16 + w*4) * 256,
                             qkv + (size_t)((kt+1)*64 + i*16 + srK) * 6144 + 4096 + kvh*128 + scK*8);
#pragma unroll
            for (int i = 0; i < 4; ++i)
                async_copy16(vbn + (i*32 + w*8) * 128,
                             vT + (size_t)(kvh*128 + i*32 + srV) * 2048 + (kt+1)*64 + scV*8);
        }

        if (kt*64 <= qrow0 + 31) {
            f32x4 st[2][4] = {};
            __builtin_amdgcn_s_setprio(1);
#pragma unroll
            for (int dks = 0; dks < 4; ++dks) {
                bf16x8 kf[4];
#pragma unroll
                for (int j = 0; j < 4; ++j) {
                    const int row = j*16 + c0;
                    kf[j] = *(const bf16x8*)(kb + row*256 + (((dks*4 + g) ^ c0) * 16));
                }
#pragma unroll
                for (int i = 0; i < 2; ++i)
#pragma unroll
                    for (int j = 0; j < 4; ++j)
                        st[i][j] = __builtin_amdgcn_mfma_f32_16x16x32_bf16(
                            kf[j], qf[i][dks], st[i][j], 0, 0, 0);
            }
            __builtin_amdgcn_s_setprio(0);

            const bool diag = (kt*64 + 63) > qrow0;
            u32 pk[2][4][2];
#pragma unroll
            for (int i = 0; i < 2; ++i) {
                float rowsum = 0.f;
#pragma unroll
                for (int j = 0; j < 4; ++j) {
#pragma unroll
                    for (int r = 0; r < 4; ++r) {
                        float p = exp2f(st[i][j][r] * SC2);
                        if (diag) {
                            const int kgl = kt*64 + j*16 + g*4 + r;
                            const int qgl = qrow0 + i*16 + c0;
                            if (kgl > qgl) p = 0.f;
                        }
                        st[i][j][r] = p;
                        rowsum += p;
                    }
                    pk[i][j][0] = cvt_pk_bf16(st[i][j][0], st[i][j][1]);
                    pk[i][j][1] = cvt_pk_bf16(st[i][j][2], st[i][j][3]);
                }
                rowsum += __shfl_xor(rowsum, 16);
                rowsum += __shfl_xor(rowsum, 32);
                lsum[i] += rowsum;
            }

#pragma unroll
            for (int dks = 0; dks < 2; ++dks) {
                bf16x8 pf[2];
#pragma unroll
                for (int i = 0; i < 2; ++i) {
                    union { u32 u[4]; bf16x8 v; } pu;
                    pu.u[0] = pk[i][2*dks][0];   pu.u[1] = pk[i][2*dks][1];
                    pu.u[2] = pk[i][2*dks+1][0]; pu.u[3] = pk[i][2*dks+1][1];
                    pf[i] = pu.v;
                }
                __builtin_amdgcn_s_setprio(1);
#pragma unroll
                for (int dj = 0; dj < 8; ++dj) {
                    const int row = dj*16 + c0;
                    const int cg0 = (4*dks + (g >> 1)) ^ (row & 7);
                    const int cg1 = (4*dks + (g >> 1) + 2) ^ (row & 7);
                    union { struct { bf16x4 lo, hi; } p; bf16x8 v; } vu;
                    vu.p.lo = *(const bf16x4*)(vb + row*128 + cg0*16 + 8*(g & 1));
                    vu.p.hi = *(const bf16x4*)(vb + row*128 + cg1*16 + 8*(g & 1));
#pragma unroll
                    for (int i = 0; i < 2; ++i)
                        o[i][dj] = __builtin_amdgcn_mfma_f32_16x16x32_bf16(
                            vu.v, pf[i], o[i][dj], 0, 0, 0);
                }
                __builtin_amdgcn_s_setprio(0);
            }
        }
        __syncthreads();
    }

#pragma unroll
    for (int i = 0; i < 2; ++i) {
        const float rcp = 1.0f / lsum[i];
        const int qg = qrow0 + i*16 + c0;
#pragma unroll
        for (int dj = 0; dj < 8; ++dj) {
            u16x4 ov = { f32_to_bf16bits(o[i][dj][0] * rcp),
                         f32_to_bf16bits(o[i][dj][1] * rcp),
                         f32_to_bf16bits(o[i][dj][2] * rcp),
                         f32_to_bf16bits(o[i][dj][3] * rcp) };
            *(u16x4*)(outp + (size_t)qg * 4096 + h*128 + dj*16 + g*4) = ov;
        }
    }
}

// ---------------------------------------------------------------- launcher
extern "C" void kernel_launch(void* const* d_in, const int* in_sizes, int n_in,
                              void* d_out, int out_size, void* d_ws, size_t ws_size,
                              hipStream_t stream) {
    const float* x    = (const float*)d_in[0];
    const float* wq   = (const float*)d_in[1];
    const float* wk   = (const float*)d_in[2];
    const float* wv   = (const float*)d_in[3];
    const float* wo   = (const float*)d_in[4];
    const float* cosp = (const float*)d_in[5];
    const float* sinp = (const float*)d_in[6];
    // d_in[7] = mask — causality applied analytically in attn_kernel.

    char* ws = (char*)d_ws;
    u16* xb    = (u16*)(ws);                       //  16.8 MB  x bf16 (2048x4096)
    u16* wqkvT = (u16*)(ws + 16777216);            //  50.3 MB  [wq|wk|wv]^T (6144x4096)
    u16* woT   = (u16*)(ws + 67108864);            //  33.6 MB  wo^T (4096x4096)
    u16* qkv   = (u16*)(ws + 100663296);           //  25.2 MB  qkv (2048x6144)
    u16* vTb   = (u16*)(ws + 125829120);           //   4.2 MB  v^T (1024x2048)
    u16* attn  = (u16*)(ws + 130023424);           //  16.8 MB  attn out (2048x4096)

    dim3 tb(32, 8);
    convert_f32_bf16<<<8192, 256, 0, stream>>>(x, xb, 2097152);
    transpose_wT<<<dim3(32, 128), tb, 0, stream>>>(wq, wqkvT, 4096, 4096);
    transpose_wT<<<dim3(8, 128),  tb, 0, stream>>>(wk, wqkvT + (size_t)4096*4096, 1024, 4096);
    transpose_wT<<<dim3(8, 128),  tb, 0, stream>>>(wv, wqkvT + (size_t)5120*4096, 1024, 4096);
    transpose_wT<<<dim3(32, 128), tb, 0, stream>>>(wo, woT, 4096, 4096);

    gemm_qkv<<<256, 512, 0, stream>>>(xb, wqkvT, qkv, 6144, 4096);
    rope_kernel<<<dim3(2048, 10), 256, 0, stream>>>((u32*)qkv, cosp, sinp);
    transpose_v<<<dim3(64, 32), tb, 0, stream>>>(qkv, vTb);
    attn_kernel<<<dim3(16, 32), 256, 0, stream>>>(qkv, vTb, attn);
    gemm_out<<<256, 512, 0, stream>>>(attn, woT, (float*)d_out, 4096, 4096);
}